// Round 11
// baseline (418.993 us; speedup 1.0000x reference)
//
#include <hip/hip_runtime.h>
#include <math.h>

#define NTOK 2048
#define DMODEL 1024
#define NHEAD 16
#define DHEAD 64
#define NCH_S 4
#define NCH_A 2
#define TIL_S (NTOK / 64 / NCH_S)   // 8 tiles per stats chunk
#define TIL_A (NTOK / 64 / NCH_A)   // 16 tiles per attnpv chunk

typedef _Float16 f16x8 __attribute__((ext_vector_type(8)));
typedef _Float16 f16x4 __attribute__((ext_vector_type(4)));
typedef _Float16 f16x2 __attribute__((ext_vector_type(2)));
typedef float f32x4 __attribute__((ext_vector_type(4)));
typedef float f32x16 __attribute__((ext_vector_type(16)));

union U32H2 { f16x2 h; unsigned u; };
union U8 { f16x8 v; unsigned u[4]; };

__device__ __forceinline__ void split16(float x, _Float16& hi, _Float16& lo) {
    hi = (_Float16)x;
    lo = (_Float16)(x - (float)hi);
}
__device__ __forceinline__ unsigned packh(_Float16 a, _Float16 b) {
    U32H2 c; c.h = f16x2{a, b}; return c.u;
}

// ---------- prep: W[k][n] f32 -> Wt_hi/Wt_lo [n][k] f16, 4 matrices ----------
__global__ void __launch_bounds__(256) prep_w_kernel(
        const float* __restrict__ Wq, const float* __restrict__ Wk,
        const float* __restrict__ Wv, const float* __restrict__ Wo,
        _Float16* __restrict__ Wt) {
    __shared__ float T[32][33];
    const int z = blockIdx.z;
    const float* W = (z == 0) ? Wq : (z == 1) ? Wk : (z == 2) ? Wv : Wo;
    _Float16* Whi = Wt + (size_t)z * 2 * 1024 * 1024;
    _Float16* Wlo = Whi + (size_t)1024 * 1024;
    const int t = threadIdx.x;
    const int k0 = blockIdx.y * 32, n0 = blockIdx.x * 32;
    const int r = t >> 3, c4 = (t & 7) * 4;
    const float4 v = *(const float4*)(W + (size_t)(k0 + r) * DMODEL + n0 + c4);
    T[r][c4 + 0] = v.x; T[r][c4 + 1] = v.y; T[r][c4 + 2] = v.z; T[r][c4 + 3] = v.w;
    __syncthreads();
    f16x4 hv, lv;
#pragma unroll
    for (int j = 0; j < 4; ++j) {
        _Float16 h, l;
        split16(T[c4 + j][r], h, l);
        hv[j] = h; lv[j] = l;
    }
    *(f16x4*)(Whi + (size_t)(n0 + r) * DMODEL + k0 + c4) = hv;
    *(f16x4*)(Wlo + (size_t)(n0 + r) * DMODEL + k0 + c4) = lv;
}

// ---------- prep: A (query/key/value) f32 -> hi/lo f16 planes ----------
__global__ void __launch_bounds__(256) prep_a_kernel(
        const float* __restrict__ q, const float* __restrict__ k, const float* __restrict__ v,
        _Float16* __restrict__ As) {   // layout: [z][hi/lo][2048*1024]
    const int z = blockIdx.y;
    const float* A = (z == 0) ? q : (z == 1) ? k : v;
    const size_t PL = (size_t)NTOK * DMODEL;
    _Float16* H = As + (size_t)z * 2 * PL;
    _Float16* L = H + PL;
    const size_t off = ((size_t)blockIdx.x * 256 + threadIdx.x) * 8;
    const float4 a = *(const float4*)(A + off);
    const float4 b = *(const float4*)(A + off + 4);
    f16x8 hv, lv; _Float16 h, lo;
    split16(a.x, h, lo); hv[0] = h; lv[0] = lo;
    split16(a.y, h, lo); hv[1] = h; lv[1] = lo;
    split16(a.z, h, lo); hv[2] = h; lv[2] = lo;
    split16(a.w, h, lo); hv[3] = h; lv[3] = lo;
    split16(b.x, h, lo); hv[4] = h; lv[4] = lo;
    split16(b.y, h, lo); hv[5] = h; lv[5] = lo;
    split16(b.z, h, lo); hv[6] = h; lv[6] = lo;
    split16(b.w, h, lo); hv[7] = h; lv[7] = lo;
    *(f16x8*)(H + off) = hv;
    *(f16x8*)(L + off) = lv;
}

// ---------- QKV projection: pre-split f16 MFMA GEMM, 64x128 tile, grid-balanced ----------
__global__ void __launch_bounds__(256) qkv_mfma_kernel(
        const _Float16* __restrict__ As,
        const _Float16* __restrict__ Wt,
        const float* __restrict__ bq, const float* __restrict__ bk, const float* __restrict__ bv,
        _Float16* __restrict__ Qh, _Float16* __restrict__ Ql,
        _Float16* __restrict__ Kh, _Float16* __restrict__ Kl,
        _Float16* __restrict__ Vth, _Float16* __restrict__ Vtl) {
    __shared__ _Float16 Ah[64][40], Al[64][40], Bh[128][40], Bl[128][40];
    const int z = blockIdx.z;
    const size_t PL = (size_t)NTOK * DMODEL;
    const _Float16* AH = As + (size_t)z * 2 * PL;
    const _Float16* AL = AH + PL;
    const _Float16* WH = Wt + (size_t)z * 2 * 1024 * 1024;
    const _Float16* WL = WH + (size_t)1024 * 1024;
    const float* bias = (z == 0) ? bq : (z == 1) ? bk : bv;

    const int t = threadIdx.x;
    const int l = t & 63, wid = t >> 6;
    const int lr = l & 15, lk = l >> 4;
    const int m0 = blockIdx.y * 64, n0 = blockIdx.x * 128;
    const int wm = (wid >> 1) * 32, wn = (wid & 1) * 64;

    f32x4 acc[2][4];
#pragma unroll
    for (int mi = 0; mi < 2; ++mi)
#pragma unroll
        for (int ni = 0; ni < 4; ++ni)
#pragma unroll
            for (int e = 0; e < 4; ++e) acc[mi][ni][e] = 0.f;

    for (int k0 = 0; k0 < DMODEL; k0 += 32) {
        __syncthreads();
        {   // A: pre-split f16, 64x32 per plane
            const int r = t >> 2, c8 = (t & 3) * 8;
            *(f16x8*)&Ah[r][c8] = *(const f16x8*)(AH + (size_t)(m0 + r) * DMODEL + k0 + c8);
            *(f16x8*)&Al[r][c8] = *(const f16x8*)(AL + (size_t)(m0 + r) * DMODEL + k0 + c8);
        }
#pragma unroll
        for (int p = 0; p < 2; ++p) {   // B: 128x32 per plane
            const int idx = t + p * 256;
            const int r = idx >> 2, c8 = (idx & 3) * 8;
            *(f16x8*)&Bh[r][c8] = *(const f16x8*)(WH + (size_t)(n0 + r) * DMODEL + k0 + c8);
            *(f16x8*)&Bl[r][c8] = *(const f16x8*)(WL + (size_t)(n0 + r) * DMODEL + k0 + c8);
        }
        __syncthreads();

        f16x8 ah[2], al[2], bh[4], bl[4];
#pragma unroll
        for (int i = 0; i < 2; ++i) {
            ah[i] = *(f16x8*)&Ah[wm + i * 16 + lr][lk * 8];
            al[i] = *(f16x8*)&Al[wm + i * 16 + lr][lk * 8];
        }
#pragma unroll
        for (int i = 0; i < 4; ++i) {
            bh[i] = *(f16x8*)&Bh[wn + i * 16 + lr][lk * 8];
            bl[i] = *(f16x8*)&Bl[wn + i * 16 + lr][lk * 8];
        }
        __builtin_amdgcn_s_setprio(1);
#pragma unroll
        for (int mi = 0; mi < 2; ++mi)
#pragma unroll
            for (int ni = 0; ni < 4; ++ni) {
                acc[mi][ni] = __builtin_amdgcn_mfma_f32_16x16x32_f16(ah[mi], bh[ni], acc[mi][ni], 0, 0, 0);
                acc[mi][ni] = __builtin_amdgcn_mfma_f32_16x16x32_f16(ah[mi], bl[ni], acc[mi][ni], 0, 0, 0);
                acc[mi][ni] = __builtin_amdgcn_mfma_f32_16x16x32_f16(al[mi], bh[ni], acc[mi][ni], 0, 0, 0);
            }
        __builtin_amdgcn_s_setprio(0);
    }

#pragma unroll
    for (int ni = 0; ni < 4; ++ni) {
        const int col = n0 + wn + ni * 16 + lr;
        const float bv_ = bias[col];
#pragma unroll
        for (int mi = 0; mi < 2; ++mi) {
            if (z == 2) {
                f16x4 hv, lv;
#pragma unroll
                for (int i = 0; i < 4; ++i) {
                    _Float16 h, lo;
                    split16(acc[mi][ni][i] + bv_, h, lo);
                    hv[i] = h; lv[i] = lo;
                }
                const int row = m0 + wm + mi * 16 + lk * 4;
                *(f16x4*)(Vth + (size_t)col * NTOK + row) = hv;
                *(f16x4*)(Vtl + (size_t)col * NTOK + row) = lv;
            } else {
#pragma unroll
                for (int i = 0; i < 4; ++i) {
                    const int row = m0 + wm + mi * 16 + lk * 4 + i;
                    float v = acc[mi][ni][i] + bv_;
                    if (z == 0) v *= 0.125f;
                    _Float16 h, lo;
                    split16(v, h, lo);
                    if (z == 0) { Qh[(size_t)row * DMODEL + col] = h; Ql[(size_t)row * DMODEL + col] = lo; }
                    else        { Kh[(size_t)row * DMODEL + col] = h; Kl[(size_t)row * DMODEL + col] = lo; }
                }
            }
        }
    }
}

// ---------- stats: l = sum exp(s), 2-term split (K hi only), 32x32 swapped QKT ----------
// grid (16, 16, NCH_S); block 256 = 4 waves x 32 q rows. LDS 16KB.
__global__ void __launch_bounds__(256, 4) stats_kernel(
        const _Float16* __restrict__ Qh, const _Float16* __restrict__ Ql,
        const _Float16* __restrict__ Kh,
        float* __restrict__ lpart) {
    __shared__ _Float16 KB[2][64][64];
    const int t = threadIdx.x, l = t & 63, w = t >> 6, q = l & 31, h = l >> 5;
    const int hh = blockIdx.y, z = blockIdx.z;
    const int rw = blockIdx.x * 128 + w * 32;
    const int sr = t >> 3, sc = t & 7;

    f16x8 qbh[4], qbl[4];
#pragma unroll
    for (int s = 0; s < 4; ++s) {
        const size_t off = (size_t)(rw + q) * DMODEL + hh * DHEAD + s * 16 + h * 8;
        qbh[s] = *(const f16x8*)(Qh + off);
        qbl[s] = *(const f16x8*)(Ql + off);
    }

    float lsum = 0.f;
    {
        const int j0 = z * TIL_S * 64;
        const int r = sr, r2 = sr + 32;
        *(f16x8*)&KB[0][r][(sc ^ (r & 7)) * 8]   = *(const f16x8*)(Kh + (size_t)(j0 + r) * DMODEL + hh * DHEAD + sc * 8);
        *(f16x8*)&KB[0][r2][(sc ^ (r2 & 7)) * 8] = *(const f16x8*)(Kh + (size_t)(j0 + r2) * DMODEL + hh * DHEAD + sc * 8);
    }
    for (int it = 0; it < TIL_S; ++it) {
        __syncthreads();
        const int cur = it & 1;
        if (it + 1 < TIL_S) {
            const int j0 = (z * TIL_S + it + 1) * 64;
            const int r = sr, r2 = sr + 32;
            *(f16x8*)&KB[cur ^ 1][r][(sc ^ (r & 7)) * 8]   = *(const f16x8*)(Kh + (size_t)(j0 + r) * DMODEL + hh * DHEAD + sc * 8);
            *(f16x8*)&KB[cur ^ 1][r2][(sc ^ (r2 & 7)) * 8] = *(const f16x8*)(Kh + (size_t)(j0 + r2) * DMODEL + hh * DHEAD + sc * 8);
        }
#pragma unroll
        for (int kb = 0; kb < 2; ++kb) {
            f32x16 c;
#pragma unroll
            for (int r = 0; r < 16; ++r) c[r] = 0.f;
            __builtin_amdgcn_s_setprio(1);
#pragma unroll
            for (int s = 0; s < 4; ++s) {
                const int rk = kb * 32 + q; const int cc = ((2 * s + h) ^ (rk & 7)) * 8;
                const f16x8 ah = *(f16x8*)&KB[cur][rk][cc];
                c = __builtin_amdgcn_mfma_f32_32x32x16_f16(ah, qbh[s], c, 0, 0, 0);
                c = __builtin_amdgcn_mfma_f32_32x32x16_f16(ah, qbl[s], c, 0, 0, 0);
            }
            __builtin_amdgcn_s_setprio(0);
#pragma unroll
            for (int r = 0; r < 16; ++r) lsum += __expf(c[r]);
        }
    }
    lsum += __shfl_xor(lsum, 32);
    if (h == 0) lpart[((size_t)z * NHEAD + hh) * NTOK + rw + q] = lsum;
}

// ---------- attn + PV: 32x32 swapped QKT, in-register P, dbuf K+V (R7 form) ----------
// grid (16, 16, NCH_A); block 256 = 4 waves x 32 q rows. LDS 64KB, 2 blocks/CU.
__global__ void __launch_bounds__(256, 2) attnpv_kernel(
        const _Float16* __restrict__ Qh, const _Float16* __restrict__ Ql,
        const _Float16* __restrict__ Kh, const _Float16* __restrict__ Kl,
        const _Float16* __restrict__ Vth, const _Float16* __restrict__ Vtl,
        const float* __restrict__ lpart,
        float* __restrict__ attn, float* __restrict__ Xp0, float* __restrict__ Xp1) {
    __shared__ _Float16 KB[2][2][64][64];
    __shared__ _Float16 VB[2][2][64][64];
    const int t = threadIdx.x, l = t & 63, w = t >> 6, q = l & 31, h = l >> 5;
    const int hh = blockIdx.y, z = blockIdx.z;
    const int rw = blockIdx.x * 128 + w * 32;
    const int sr = t >> 3, sc = t & 7;
    const int qrow = rw + q;

    float lsum = 0.f;
#pragma unroll
    for (int zz = 0; zz < NCH_S; ++zz) lsum += lpart[((size_t)zz * NHEAD + hh) * NTOK + qrow];
    const float linv = 1.f / lsum;

    f16x8 qbh[4], qbl[4];
#pragma unroll
    for (int s = 0; s < 4; ++s) {
        const size_t off = (size_t)qrow * DMODEL + hh * DHEAD + s * 16 + h * 8;
        qbh[s] = *(const f16x8*)(Qh + off);
        qbl[s] = *(const f16x8*)(Ql + off);
    }

    f32x16 x0, x1;
#pragma unroll
    for (int r = 0; r < 16; ++r) { x0[r] = 0.f; x1[r] = 0.f; }

    auto stage = [&](int buf, int j0) {
#pragma unroll
        for (int p = 0; p < 2; ++p) {
            const int r = sr + p * 32; const int cs = (sc ^ (r & 7)) * 8;
            *(f16x8*)&KB[buf][0][r][cs] = *(const f16x8*)(Kh + (size_t)(j0 + r) * DMODEL + hh * DHEAD + sc * 8);
            *(f16x8*)&KB[buf][1][r][cs] = *(const f16x8*)(Kl + (size_t)(j0 + r) * DMODEL + hh * DHEAD + sc * 8);
            *(f16x8*)&VB[buf][0][r][cs] = *(const f16x8*)(Vth + (size_t)(hh * DHEAD + r) * NTOK + j0 + sc * 8);
            *(f16x8*)&VB[buf][1][r][cs] = *(const f16x8*)(Vtl + (size_t)(hh * DHEAD + r) * NTOK + j0 + sc * 8);
        }
    };
    stage(0, z * TIL_A * 64);

    for (int it = 0; it < TIL_A; ++it) {
        const int j0 = (z * TIL_A + it) * 64;
        __syncthreads();
        const int cur = it & 1;
        if (it + 1 < TIL_A) stage(cur ^ 1, (z * TIL_A + it + 1) * 64);

#pragma unroll
        for (int kb = 0; kb < 2; ++kb) {
            f32x16 c;
#pragma unroll
            for (int r = 0; r < 16; ++r) c[r] = 0.f;
            __builtin_amdgcn_s_setprio(1);
#pragma unroll
            for (int s = 0; s < 4; ++s) {
                const int rk = kb * 32 + q; const int cc = ((2 * s + h) ^ (rk & 7)) * 8;
                const f16x8 ah = *(f16x8*)&KB[cur][0][rk][cc];
                const f16x8 al = *(f16x8*)&KB[cur][1][rk][cc];
                c = __builtin_amdgcn_mfma_f32_32x32x16_f16(ah, qbh[s], c, 0, 0, 0);
                c = __builtin_amdgcn_mfma_f32_32x32x16_f16(ah, qbl[s], c, 0, 0, 0);
                c = __builtin_amdgcn_mfma_f32_32x32x16_f16(al, qbh[s], c, 0, 0, 0);
            }
            __builtin_amdgcn_s_setprio(0);

            float p[16];
#pragma unroll
            for (int r = 0; r < 16; ++r) p[r] = __expf(c[r]) * linv;

            const int kbase = j0 + kb * 32;
#pragma unroll
            for (int i = 0; i < 4; ++i) {
                f32x4 st;
                st[0] = p[4 * i]; st[1] = p[4 * i + 1]; st[2] = p[4 * i + 2]; st[3] = p[4 * i + 3];
                __builtin_nontemporal_store(
                    st, (f32x4*)(attn + ((size_t)hh * NTOK + qrow) * NTOK + kbase + 8 * i + 4 * h));
            }

            _Float16 hf[16], lf[16];
#pragma unroll
            for (int r = 0; r < 16; ++r) {
                hf[r] = (_Float16)p[r];
                lf[r] = (_Float16)(p[r] - (float)hf[r]);
            }
            unsigned ph[8], pl[8];
#pragma unroll
            for (int i = 0; i < 8; ++i) {
                ph[i] = packh(hf[2 * i], hf[2 * i + 1]);
                pl[i] = packh(lf[2 * i], lf[2 * i + 1]);
            }

#pragma unroll
            for (int ss = 0; ss < 2; ++ss) {
                const int b = 4 * ss;
                const unsigned eh0 = __shfl_xor(h ? ph[b + 0] : ph[b + 2], 32);
                const unsigned eh1 = __shfl_xor(h ? ph[b + 1] : ph[b + 3], 32);
                const unsigned el0 = __shfl_xor(h ? pl[b + 0] : pl[b + 2], 32);
                const unsigned el1 = __shfl_xor(h ? pl[b + 1] : pl[b + 3], 32);
                U8 pah, pal;
                pah.u[0] = h ? eh0 : ph[b + 0]; pah.u[1] = h ? eh1 : ph[b + 1];
                pah.u[2] = h ? ph[b + 2] : eh0; pah.u[3] = h ? ph[b + 3] : eh1;
                pal.u[0] = h ? el0 : pl[b + 0]; pal.u[1] = h ? el1 : pl[b + 1];
                pal.u[2] = h ? pl[b + 2] : el0; pal.u[3] = h ? pl[b + 3] : el1;
                const int ks = kb * 2 + ss;
                __builtin_amdgcn_s_setprio(1);
                {
                    const int rd0 = q; const int cv0 = ((2 * ks + h) ^ (rd0 & 7)) * 8;
                    const f16x8 vh = *(f16x8*)&VB[cur][0][rd0][cv0];
                    const f16x8 vl = *(f16x8*)&VB[cur][1][rd0][cv0];
                    x0 = __builtin_amdgcn_mfma_f32_32x32x16_f16(pah.v, vh, x0, 0, 0, 0);
                    x0 = __builtin_amdgcn_mfma_f32_32x32x16_f16(pah.v, vl, x0, 0, 0, 0);
                    x0 = __builtin_amdgcn_mfma_f32_32x32x16_f16(pal.v, vh, x0, 0, 0, 0);
                }
                {
                    const int rd1 = 32 + q; const int cv1 = ((2 * ks + h) ^ (rd1 & 7)) * 8;
                    const f16x8 vh = *(f16x8*)&VB[cur][0][rd1][cv1];
                    const f16x8 vl = *(f16x8*)&VB[cur][1][rd1][cv1];
                    x1 = __builtin_amdgcn_mfma_f32_32x32x16_f16(pah.v, vh, x1, 0, 0, 0);
                    x1 = __builtin_amdgcn_mfma_f32_32x32x16_f16(pah.v, vl, x1, 0, 0, 0);
                    x1 = __builtin_amdgcn_mfma_f32_32x32x16_f16(pal.v, vh, x1, 0, 0, 0);
                }
                __builtin_amdgcn_s_setprio(0);
            }
        }
    }

    float* __restrict__ Xout = z ? Xp1 : Xp0;
#pragma unroll
    for (int r = 0; r < 16; ++r) {
        const int qloc = (r & 3) + 8 * (r >> 2) + 4 * h;
        Xout[(size_t)(rw + qloc) * DMODEL + hh * DHEAD + q]      = x0[r];
        Xout[(size_t)(rw + qloc) * DMODEL + hh * DHEAD + 32 + q] = x1[r];
    }
}

// ---------- output projection: A = Xp0+Xp1 (f32) -> split, 64x128 tile ----------
__global__ void __launch_bounds__(256) out_mfma_kernel(
        const float* __restrict__ Xp0, const float* __restrict__ Xp1,
        const _Float16* __restrict__ WH, const _Float16* __restrict__ WL,
        const float* __restrict__ bo, float* __restrict__ out) {
    __shared__ _Float16 Ah[64][40], Al[64][40], Bh[128][40], Bl[128][40];
    const int t = threadIdx.x;
    const int l = t & 63, wid = t >> 6;
    const int lr = l & 15, lk = l >> 4;
    const int m0 = blockIdx.y * 64, n0 = blockIdx.x * 128;
    const int wm = (wid >> 1) * 32, wn = (wid & 1) * 64;

    f32x4 acc[2][4];
#pragma unroll
    for (int mi = 0; mi < 2; ++mi)
#pragma unroll
        for (int ni = 0; ni < 4; ++ni)
#pragma unroll
            for (int e = 0; e < 4; ++e) acc[mi][ni][e] = 0.f;

    for (int k0 = 0; k0 < DMODEL; k0 += 32) {
        __syncthreads();
#pragma unroll
        for (int p = 0; p < 2; ++p) {
            const int idx = t + p * 256;
            const int r = idx >> 3, c4 = (idx & 7) * 4;
            const size_t off = (size_t)(m0 + r) * DMODEL + k0 + c4;
            const float4 v0 = *(const float4*)(Xp0 + off);
            const float4 v1 = *(const float4*)(Xp1 + off);
            f16x4 hv, lv; _Float16 h, lo;
            split16(v0.x + v1.x, h, lo); hv[0] = h; lv[0] = lo;
            split16(v0.y + v1.y, h, lo); hv[1] = h; lv[1] = lo;
            split16(v0.z + v1.z, h, lo); hv[2] = h; lv[2] = lo;
            split16(v0.w + v1.w, h, lo); hv[3] = h; lv[3] = lo;
            *(f16x4*)&Ah[r][c4] = hv;
            *(f16x4*)&Al[r][c4] = lv;
        }
#pragma unroll
        for (int p = 0; p < 2; ++p) {
            const int idx = t + p * 256;
            const int r = idx >> 2, c8 = (idx & 3) * 8;
            *(f16x8*)&Bh[r][c8] = *(const f16x8*)(WH + (size_t)(n0 + r) * DMODEL + k0 + c8);
            *(f16x8*)&Bl[r][c8] = *(const f16x8*)(WL + (size_t)(n0 + r) * DMODEL + k0 + c8);
        }
        __syncthreads();

        f16x8 ah[2], al[2], bh[4], bl[4];
#pragma unroll
        for (int i = 0; i < 2; ++i) {
            ah[i] = *(f16x8*)&Ah[wm + i * 16 + lr][lk * 8];
            al[i] = *(f16x8*)&Al[wm + i * 16 + lr][lk * 8];
        }
#pragma unroll
        for (int i = 0; i < 4; ++i) {
            bh[i] = *(f16x8*)&Bh[wn + i * 16 + lr][lk * 8];
            bl[i] = *(f16x8*)&Bl[wn + i * 16 + lr][lk * 8];
        }
        __builtin_amdgcn_s_setprio(1);
#pragma unroll
        for (int mi = 0; mi < 2; ++mi)
#pragma unroll
            for (int ni = 0; ni < 4; ++ni) {
                acc[mi][ni] = __builtin_amdgcn_mfma_f32_16x16x32_f16(ah[mi], bh[ni], acc[mi][ni], 0, 0, 0);
                acc[mi][ni] = __builtin_amdgcn_mfma_f32_16x16x32_f16(ah[mi], bl[ni], acc[mi][ni], 0, 0, 0);
                acc[mi][ni] = __builtin_amdgcn_mfma_f32_16x16x32_f16(al[mi], bh[ni], acc[mi][ni], 0, 0, 0);
            }
        __builtin_amdgcn_s_setprio(0);
    }

#pragma unroll
    for (int ni = 0; ni < 4; ++ni) {
        const int col = n0 + wn + ni * 16 + lr;
        const float bv_ = bo[col];
#pragma unroll
        for (int mi = 0; mi < 2; ++mi)
#pragma unroll
            for (int i = 0; i < 4; ++i) {
                const int row = m0 + wm + mi * 16 + lk * 4 + i;
                out[(size_t)row * DMODEL + col] = acc[mi][ni][i] + bv_;
            }
    }
}

extern "C" void kernel_launch(void* const* d_in, const int* in_sizes, int n_in,
                              void* d_out, int out_size, void* d_ws, size_t ws_size,
                              hipStream_t stream) {
    (void)in_sizes; (void)n_in; (void)out_size; (void)ws_size;
    const float* query = (const float*)d_in[0];
    const float* key_  = (const float*)d_in[1];
    const float* value = (const float*)d_in[2];
    const float* Wq = (const float*)d_in[3];
    const float* bq = (const float*)d_in[4];
    const float* Wk = (const float*)d_in[5];
    const float* bk = (const float*)d_in[6];
    const float* Wv = (const float*)d_in[7];
    const float* bv = (const float*)d_in[8];
    const float* Wo = (const float*)d_in[9];
    const float* bo = (const float*)d_in[10];

    float* out  = (float*)d_out;
    float* attn = out + (size_t)NTOK * DMODEL;

    const size_t MM = (size_t)1024 * 1024;
    _Float16* ws16 = (_Float16*)d_ws;          // 48 MB total
    _Float16* Wt  = ws16;                      // 8 planes (Wq,Wk,Wv,Wo x hi/lo), 16 MB
    _Float16* Qh  = ws16 + 8 * MM;             // 6 x 4 MB QKV planes
    _Float16* Ql  = Qh  + 2 * MM;
    _Float16* Kh_ = Ql  + 2 * MM;
    _Float16* Kl_ = Kh_ + 2 * MM;
    _Float16* Vth = Kl_ + 2 * MM;
    _Float16* Vtl = Vth + 2 * MM;

    // dead-after-qkv aliases: Xp0 over Wq/Wk planes; lpart over Wv hi plane
    float* Xp0   = (float*)ws16;                               // 8 MB over Wt[0..4MM)
    float* lpart = (float*)(ws16 + 4 * MM);                    // 512 KB over Wv_hi
    float* Xp1   = (float*)(ws16 + 20 * MM);                   // fresh 8 MB

    // A-split scratch lives in the attn output region (dead until attnpv rewrites it)
    _Float16* As = (_Float16*)attn;                            // 12 MB of 268 MB

    dim3 blk(256);
    prep_w_kernel<<<dim3(32, 32, 4), blk, 0, stream>>>(Wq, Wk, Wv, Wo, Wt);
    prep_a_kernel<<<dim3(1024, 3), blk, 0, stream>>>(query, key_, value, As);
    qkv_mfma_kernel<<<dim3(8, 32, 3), blk, 0, stream>>>(As, Wt, bq, bk, bv,
                                                        Qh, Ql, Kh_, Kl_, Vth, Vtl);
    stats_kernel<<<dim3(16, 16, NCH_S), blk, 0, stream>>>(Qh, Ql, Kh_, lpart);
    attnpv_kernel<<<dim3(16, 16, NCH_A), blk, 0, stream>>>(Qh, Ql, Kh_, Kl_, Vth, Vtl,
                                                           lpart, attn, Xp0, Xp1);
    out_mfma_kernel<<<dim3(8, 32), blk, 0, stream>>>(Xp0, Xp1, Wt + 6 * MM, Wt + 7 * MM, bo, out);
}

// Round 12
// 240.493 us; speedup vs baseline: 1.7422x; 1.7422x over previous
//
#include <hip/hip_runtime.h>
#include <math.h>

#define NTOK 2048
#define DMODEL 1024
#define NHEAD 16
#define DHEAD 64
#define NCH_S 4
#define NCH_A 2
#define TIL_S (NTOK / 64 / NCH_S)   // 8 tiles per stats chunk
#define TIL_A (NTOK / 64 / NCH_A)   // 16 tiles per attnpv chunk

typedef _Float16 f16x8 __attribute__((ext_vector_type(8)));
typedef _Float16 f16x4 __attribute__((ext_vector_type(4)));
typedef _Float16 f16x2 __attribute__((ext_vector_type(2)));
typedef float f32x4 __attribute__((ext_vector_type(4)));
typedef float f32x16 __attribute__((ext_vector_type(16)));

union U32H2 { f16x2 h; unsigned u; };
union U8 { f16x8 v; unsigned u[4]; };

__device__ __forceinline__ void split16(float x, _Float16& hi, _Float16& lo) {
    hi = (_Float16)x;
    lo = (_Float16)(x - (float)hi);
}
__device__ __forceinline__ unsigned packh(_Float16 a, _Float16 b) {
    U32H2 c; c.h = f16x2{a, b}; return c.u;
}

// ---------- prep: W[k][n] f32 -> Wt_hi/Wt_lo [n][k] f16, 4 matrices ----------
__global__ void __launch_bounds__(256) prep_w_kernel(
        const float* __restrict__ Wq, const float* __restrict__ Wk,
        const float* __restrict__ Wv, const float* __restrict__ Wo,
        _Float16* __restrict__ Wt) {
    __shared__ float T[32][33];
    const int z = blockIdx.z;
    const float* W = (z == 0) ? Wq : (z == 1) ? Wk : (z == 2) ? Wv : Wo;
    _Float16* Whi = Wt + (size_t)z * 2 * 1024 * 1024;
    _Float16* Wlo = Whi + (size_t)1024 * 1024;
    const int t = threadIdx.x;
    const int k0 = blockIdx.y * 32, n0 = blockIdx.x * 32;
    const int r = t >> 3, c4 = (t & 7) * 4;
    const float4 v = *(const float4*)(W + (size_t)(k0 + r) * DMODEL + n0 + c4);
    T[r][c4 + 0] = v.x; T[r][c4 + 1] = v.y; T[r][c4 + 2] = v.z; T[r][c4 + 3] = v.w;
    __syncthreads();
    f16x4 hv, lv;
#pragma unroll
    for (int j = 0; j < 4; ++j) {
        _Float16 h, l;
        split16(T[c4 + j][r], h, l);
        hv[j] = h; lv[j] = l;
    }
    *(f16x4*)(Whi + (size_t)(n0 + r) * DMODEL + k0 + c4) = hv;
    *(f16x4*)(Wlo + (size_t)(n0 + r) * DMODEL + k0 + c4) = lv;
}

// ---------- prep: A (query/key/value) f32 -> hi/lo f16 planes ----------
__global__ void __launch_bounds__(256) prep_a_kernel(
        const float* __restrict__ q, const float* __restrict__ k, const float* __restrict__ v,
        _Float16* __restrict__ As) {   // layout: [z][hi/lo][2048*1024]
    const int z = blockIdx.y;
    const float* A = (z == 0) ? q : (z == 1) ? k : v;
    const size_t PL = (size_t)NTOK * DMODEL;
    _Float16* H = As + (size_t)z * 2 * PL;
    _Float16* L = H + PL;
    const size_t off = ((size_t)blockIdx.x * 256 + threadIdx.x) * 8;
    const float4 a = *(const float4*)(A + off);
    const float4 b = *(const float4*)(A + off + 4);
    f16x8 hv, lv; _Float16 h, lo;
    split16(a.x, h, lo); hv[0] = h; lv[0] = lo;
    split16(a.y, h, lo); hv[1] = h; lv[1] = lo;
    split16(a.z, h, lo); hv[2] = h; lv[2] = lo;
    split16(a.w, h, lo); hv[3] = h; lv[3] = lo;
    split16(b.x, h, lo); hv[4] = h; lv[4] = lo;
    split16(b.y, h, lo); hv[5] = h; lv[5] = lo;
    split16(b.z, h, lo); hv[6] = h; lv[6] = lo;
    split16(b.w, h, lo); hv[7] = h; lv[7] = lo;
    *(f16x8*)(H + off) = hv;
    *(f16x8*)(L + off) = lv;
}

// ---------- QKV projection: pre-split f16 MFMA GEMM, 64x128 tile, grid-balanced ----------
__global__ void __launch_bounds__(256) qkv_mfma_kernel(
        const _Float16* __restrict__ As,
        const _Float16* __restrict__ Wt,
        const float* __restrict__ bq, const float* __restrict__ bk, const float* __restrict__ bv,
        _Float16* __restrict__ Qh, _Float16* __restrict__ Ql,
        _Float16* __restrict__ Kh, _Float16* __restrict__ Kl,
        _Float16* __restrict__ Vth, _Float16* __restrict__ Vtl) {
    __shared__ _Float16 Ah[64][40], Al[64][40], Bh[128][40], Bl[128][40];
    const int z = blockIdx.z;
    const size_t PL = (size_t)NTOK * DMODEL;
    const _Float16* AH = As + (size_t)z * 2 * PL;
    const _Float16* AL = AH + PL;
    const _Float16* WH = Wt + (size_t)z * 2 * 1024 * 1024;
    const _Float16* WL = WH + (size_t)1024 * 1024;
    const float* bias = (z == 0) ? bq : (z == 1) ? bk : bv;

    const int t = threadIdx.x;
    const int l = t & 63, wid = t >> 6;
    const int lr = l & 15, lk = l >> 4;
    const int m0 = blockIdx.y * 64, n0 = blockIdx.x * 128;
    const int wm = (wid >> 1) * 32, wn = (wid & 1) * 64;

    f32x4 acc[2][4];
#pragma unroll
    for (int mi = 0; mi < 2; ++mi)
#pragma unroll
        for (int ni = 0; ni < 4; ++ni)
#pragma unroll
            for (int e = 0; e < 4; ++e) acc[mi][ni][e] = 0.f;

    for (int k0 = 0; k0 < DMODEL; k0 += 32) {
        __syncthreads();
        {   // A: pre-split f16, 64x32 per plane
            const int r = t >> 2, c8 = (t & 3) * 8;
            *(f16x8*)&Ah[r][c8] = *(const f16x8*)(AH + (size_t)(m0 + r) * DMODEL + k0 + c8);
            *(f16x8*)&Al[r][c8] = *(const f16x8*)(AL + (size_t)(m0 + r) * DMODEL + k0 + c8);
        }
#pragma unroll
        for (int p = 0; p < 2; ++p) {   // B: 128x32 per plane
            const int idx = t + p * 256;
            const int r = idx >> 2, c8 = (idx & 3) * 8;
            *(f16x8*)&Bh[r][c8] = *(const f16x8*)(WH + (size_t)(n0 + r) * DMODEL + k0 + c8);
            *(f16x8*)&Bl[r][c8] = *(const f16x8*)(WL + (size_t)(n0 + r) * DMODEL + k0 + c8);
        }
        __syncthreads();

        f16x8 ah[2], al[2], bh[4], bl[4];
#pragma unroll
        for (int i = 0; i < 2; ++i) {
            ah[i] = *(f16x8*)&Ah[wm + i * 16 + lr][lk * 8];
            al[i] = *(f16x8*)&Al[wm + i * 16 + lr][lk * 8];
        }
#pragma unroll
        for (int i = 0; i < 4; ++i) {
            bh[i] = *(f16x8*)&Bh[wn + i * 16 + lr][lk * 8];
            bl[i] = *(f16x8*)&Bl[wn + i * 16 + lr][lk * 8];
        }
        __builtin_amdgcn_s_setprio(1);
#pragma unroll
        for (int mi = 0; mi < 2; ++mi)
#pragma unroll
            for (int ni = 0; ni < 4; ++ni) {
                acc[mi][ni] = __builtin_amdgcn_mfma_f32_16x16x32_f16(ah[mi], bh[ni], acc[mi][ni], 0, 0, 0);
                acc[mi][ni] = __builtin_amdgcn_mfma_f32_16x16x32_f16(ah[mi], bl[ni], acc[mi][ni], 0, 0, 0);
                acc[mi][ni] = __builtin_amdgcn_mfma_f32_16x16x32_f16(al[mi], bh[ni], acc[mi][ni], 0, 0, 0);
            }
        __builtin_amdgcn_s_setprio(0);
    }

#pragma unroll
    for (int ni = 0; ni < 4; ++ni) {
        const int col = n0 + wn + ni * 16 + lr;
        const float bv_ = bias[col];
#pragma unroll
        for (int mi = 0; mi < 2; ++mi) {
            if (z == 2) {
                f16x4 hv, lv;
#pragma unroll
                for (int i = 0; i < 4; ++i) {
                    _Float16 h, lo;
                    split16(acc[mi][ni][i] + bv_, h, lo);
                    hv[i] = h; lv[i] = lo;
                }
                const int row = m0 + wm + mi * 16 + lk * 4;
                *(f16x4*)(Vth + (size_t)col * NTOK + row) = hv;
                *(f16x4*)(Vtl + (size_t)col * NTOK + row) = lv;
            } else {
#pragma unroll
                for (int i = 0; i < 4; ++i) {
                    const int row = m0 + wm + mi * 16 + lk * 4 + i;
                    float v = acc[mi][ni][i] + bv_;
                    if (z == 0) v *= 0.125f;
                    _Float16 h, lo;
                    split16(v, h, lo);
                    if (z == 0) { Qh[(size_t)row * DMODEL + col] = h; Ql[(size_t)row * DMODEL + col] = lo; }
                    else        { Kh[(size_t)row * DMODEL + col] = h; Kl[(size_t)row * DMODEL + col] = lo; }
                }
            }
        }
    }
}

// ---------- stats: l = sum exp(s), 2-term split (K hi only), 32x32 swapped QKT ----------
// grid (16, 16, NCH_S); block 256 = 4 waves x 32 q rows. LDS 16KB.
__global__ void __launch_bounds__(256, 4) stats_kernel(
        const _Float16* __restrict__ Qh, const _Float16* __restrict__ Ql,
        const _Float16* __restrict__ Kh,
        float* __restrict__ lpart) {
    __shared__ _Float16 KB[2][64][64];
    const int t = threadIdx.x, l = t & 63, w = t >> 6, q = l & 31, h = l >> 5;
    const int hh = blockIdx.y, z = blockIdx.z;
    const int rw = blockIdx.x * 128 + w * 32;
    const int sr = t >> 3, sc = t & 7;

    f16x8 qbh[4], qbl[4];
#pragma unroll
    for (int s = 0; s < 4; ++s) {
        const size_t off = (size_t)(rw + q) * DMODEL + hh * DHEAD + s * 16 + h * 8;
        qbh[s] = *(const f16x8*)(Qh + off);
        qbl[s] = *(const f16x8*)(Ql + off);
    }

    float lsum = 0.f;
    {
        const int j0 = z * TIL_S * 64;
        const int r = sr, r2 = sr + 32;
        *(f16x8*)&KB[0][r][(sc ^ (r & 7)) * 8]   = *(const f16x8*)(Kh + (size_t)(j0 + r) * DMODEL + hh * DHEAD + sc * 8);
        *(f16x8*)&KB[0][r2][(sc ^ (r2 & 7)) * 8] = *(const f16x8*)(Kh + (size_t)(j0 + r2) * DMODEL + hh * DHEAD + sc * 8);
    }
    for (int it = 0; it < TIL_S; ++it) {
        __syncthreads();
        const int cur = it & 1;
        if (it + 1 < TIL_S) {
            const int j0 = (z * TIL_S + it + 1) * 64;
            const int r = sr, r2 = sr + 32;
            *(f16x8*)&KB[cur ^ 1][r][(sc ^ (r & 7)) * 8]   = *(const f16x8*)(Kh + (size_t)(j0 + r) * DMODEL + hh * DHEAD + sc * 8);
            *(f16x8*)&KB[cur ^ 1][r2][(sc ^ (r2 & 7)) * 8] = *(const f16x8*)(Kh + (size_t)(j0 + r2) * DMODEL + hh * DHEAD + sc * 8);
        }
#pragma unroll
        for (int kb = 0; kb < 2; ++kb) {
            f32x16 c;
#pragma unroll
            for (int r = 0; r < 16; ++r) c[r] = 0.f;
            __builtin_amdgcn_s_setprio(1);
#pragma unroll
            for (int s = 0; s < 4; ++s) {
                const int rk = kb * 32 + q; const int cc = ((2 * s + h) ^ (rk & 7)) * 8;
                const f16x8 ah = *(f16x8*)&KB[cur][rk][cc];
                c = __builtin_amdgcn_mfma_f32_32x32x16_f16(ah, qbh[s], c, 0, 0, 0);
                c = __builtin_amdgcn_mfma_f32_32x32x16_f16(ah, qbl[s], c, 0, 0, 0);
            }
            __builtin_amdgcn_s_setprio(0);
#pragma unroll
            for (int r = 0; r < 16; ++r) lsum += __expf(c[r]);
        }
    }
    lsum += __shfl_xor(lsum, 32);
    if (h == 0) lpart[((size_t)z * NHEAD + hh) * NTOK + rw + q] = lsum;
}

// ---------- attn + PV: 32x32 swapped QKT, in-register P, dbuf K+V (R7 form) ----------
// grid (16, 16, NCH_A); block 256 = 4 waves x 32 q rows. LDS 64KB, 2 blocks/CU.
__global__ void __launch_bounds__(256, 2) attnpv_kernel(
        const _Float16* __restrict__ Qh, const _Float16* __restrict__ Ql,
        const _Float16* __restrict__ Kh, const _Float16* __restrict__ Kl,
        const _Float16* __restrict__ Vth, const _Float16* __restrict__ Vtl,
        const float* __restrict__ lpart,
        float* __restrict__ attn, float* __restrict__ Xp0, float* __restrict__ Xp1) {
    __shared__ _Float16 KB[2][2][64][64];
    __shared__ _Float16 VB[2][2][64][64];
    const int t = threadIdx.x, l = t & 63, w = t >> 6, q = l & 31, h = l >> 5;
    const int hh = blockIdx.y, z = blockIdx.z;
    const int rw = blockIdx.x * 128 + w * 32;
    const int sr = t >> 3, sc = t & 7;
    const int qrow = rw + q;

    float lsum = 0.f;
#pragma unroll
    for (int zz = 0; zz < NCH_S; ++zz) lsum += lpart[((size_t)zz * NHEAD + hh) * NTOK + qrow];
    const float linv = 1.f / lsum;

    f16x8 qbh[4], qbl[4];
#pragma unroll
    for (int s = 0; s < 4; ++s) {
        const size_t off = (size_t)qrow * DMODEL + hh * DHEAD + s * 16 + h * 8;
        qbh[s] = *(const f16x8*)(Qh + off);
        qbl[s] = *(const f16x8*)(Ql + off);
    }

    f32x16 x0, x1;
#pragma unroll
    for (int r = 0; r < 16; ++r) { x0[r] = 0.f; x1[r] = 0.f; }

    auto stage = [&](int buf, int j0) {
#pragma unroll
        for (int p = 0; p < 2; ++p) {
            const int r = sr + p * 32; const int cs = (sc ^ (r & 7)) * 8;
            *(f16x8*)&KB[buf][0][r][cs] = *(const f16x8*)(Kh + (size_t)(j0 + r) * DMODEL + hh * DHEAD + sc * 8);
            *(f16x8*)&KB[buf][1][r][cs] = *(const f16x8*)(Kl + (size_t)(j0 + r) * DMODEL + hh * DHEAD + sc * 8);
            *(f16x8*)&VB[buf][0][r][cs] = *(const f16x8*)(Vth + (size_t)(hh * DHEAD + r) * NTOK + j0 + sc * 8);
            *(f16x8*)&VB[buf][1][r][cs] = *(const f16x8*)(Vtl + (size_t)(hh * DHEAD + r) * NTOK + j0 + sc * 8);
        }
    };
    stage(0, z * TIL_A * 64);

    for (int it = 0; it < TIL_A; ++it) {
        const int j0 = (z * TIL_A + it) * 64;
        __syncthreads();
        const int cur = it & 1;
        if (it + 1 < TIL_A) stage(cur ^ 1, (z * TIL_A + it + 1) * 64);

#pragma unroll
        for (int kb = 0; kb < 2; ++kb) {
            f32x16 c;
#pragma unroll
            for (int r = 0; r < 16; ++r) c[r] = 0.f;
            __builtin_amdgcn_s_setprio(1);
#pragma unroll
            for (int s = 0; s < 4; ++s) {
                const int rk = kb * 32 + q; const int cc = ((2 * s + h) ^ (rk & 7)) * 8;
                const f16x8 ah = *(f16x8*)&KB[cur][0][rk][cc];
                const f16x8 al = *(f16x8*)&KB[cur][1][rk][cc];
                c = __builtin_amdgcn_mfma_f32_32x32x16_f16(ah, qbh[s], c, 0, 0, 0);
                c = __builtin_amdgcn_mfma_f32_32x32x16_f16(ah, qbl[s], c, 0, 0, 0);
                c = __builtin_amdgcn_mfma_f32_32x32x16_f16(al, qbh[s], c, 0, 0, 0);
            }
            __builtin_amdgcn_s_setprio(0);

            float p[16];
#pragma unroll
            for (int r = 0; r < 16; ++r) p[r] = __expf(c[r]) * linv;

            const int kbase = j0 + kb * 32;
#pragma unroll
            for (int i = 0; i < 4; ++i) {
                f32x4 st;
                st[0] = p[4 * i]; st[1] = p[4 * i + 1]; st[2] = p[4 * i + 2]; st[3] = p[4 * i + 3];
                *(f32x4*)(attn + ((size_t)hh * NTOK + qrow) * NTOK + kbase + 8 * i + 4 * h) = st;
            }

            _Float16 hf[16], lf[16];
#pragma unroll
            for (int r = 0; r < 16; ++r) {
                hf[r] = (_Float16)p[r];
                lf[r] = (_Float16)(p[r] - (float)hf[r]);
            }
            unsigned ph[8], pl[8];
#pragma unroll
            for (int i = 0; i < 8; ++i) {
                ph[i] = packh(hf[2 * i], hf[2 * i + 1]);
                pl[i] = packh(lf[2 * i], lf[2 * i + 1]);
            }

#pragma unroll
            for (int ss = 0; ss < 2; ++ss) {
                const int b = 4 * ss;
                const unsigned eh0 = __shfl_xor(h ? ph[b + 0] : ph[b + 2], 32);
                const unsigned eh1 = __shfl_xor(h ? ph[b + 1] : ph[b + 3], 32);
                const unsigned el0 = __shfl_xor(h ? pl[b + 0] : pl[b + 2], 32);
                const unsigned el1 = __shfl_xor(h ? pl[b + 1] : pl[b + 3], 32);
                U8 pah, pal;
                pah.u[0] = h ? eh0 : ph[b + 0]; pah.u[1] = h ? eh1 : ph[b + 1];
                pah.u[2] = h ? ph[b + 2] : eh0; pah.u[3] = h ? ph[b + 3] : eh1;
                pal.u[0] = h ? el0 : pl[b + 0]; pal.u[1] = h ? el1 : pl[b + 1];
                pal.u[2] = h ? pl[b + 2] : el0; pal.u[3] = h ? pl[b + 3] : el1;
                const int ks = kb * 2 + ss;
                __builtin_amdgcn_s_setprio(1);
                {
                    const int rd0 = q; const int cv0 = ((2 * ks + h) ^ (rd0 & 7)) * 8;
                    const f16x8 vh = *(f16x8*)&VB[cur][0][rd0][cv0];
                    const f16x8 vl = *(f16x8*)&VB[cur][1][rd0][cv0];
                    x0 = __builtin_amdgcn_mfma_f32_32x32x16_f16(pah.v, vh, x0, 0, 0, 0);
                    x0 = __builtin_amdgcn_mfma_f32_32x32x16_f16(pah.v, vl, x0, 0, 0, 0);
                    x0 = __builtin_amdgcn_mfma_f32_32x32x16_f16(pal.v, vh, x0, 0, 0, 0);
                }
                {
                    const int rd1 = 32 + q; const int cv1 = ((2 * ks + h) ^ (rd1 & 7)) * 8;
                    const f16x8 vh = *(f16x8*)&VB[cur][0][rd1][cv1];
                    const f16x8 vl = *(f16x8*)&VB[cur][1][rd1][cv1];
                    x1 = __builtin_amdgcn_mfma_f32_32x32x16_f16(pah.v, vh, x1, 0, 0, 0);
                    x1 = __builtin_amdgcn_mfma_f32_32x32x16_f16(pah.v, vl, x1, 0, 0, 0);
                    x1 = __builtin_amdgcn_mfma_f32_32x32x16_f16(pal.v, vh, x1, 0, 0, 0);
                }
                __builtin_amdgcn_s_setprio(0);
            }
        }
    }

    float* __restrict__ Xout = z ? Xp1 : Xp0;
#pragma unroll
    for (int r = 0; r < 16; ++r) {
        const int qloc = (r & 3) + 8 * (r >> 2) + 4 * h;
        Xout[(size_t)(rw + qloc) * DMODEL + hh * DHEAD + q]      = x0[r];
        Xout[(size_t)(rw + qloc) * DMODEL + hh * DHEAD + 32 + q] = x1[r];
    }
}

// ---------- output projection: A = Xp0+Xp1 (f32) -> split, 64x128 tile ----------
__global__ void __launch_bounds__(256) out_mfma_kernel(
        const float* __restrict__ Xp0, const float* __restrict__ Xp1,
        const _Float16* __restrict__ WH, const _Float16* __restrict__ WL,
        const float* __restrict__ bo, float* __restrict__ out) {
    __shared__ _Float16 Ah[64][40], Al[64][40], Bh[128][40], Bl[128][40];
    const int t = threadIdx.x;
    const int l = t & 63, wid = t >> 6;
    const int lr = l & 15, lk = l >> 4;
    const int m0 = blockIdx.y * 64, n0 = blockIdx.x * 128;
    const int wm = (wid >> 1) * 32, wn = (wid & 1) * 64;

    f32x4 acc[2][4];
#pragma unroll
    for (int mi = 0; mi < 2; ++mi)
#pragma unroll
        for (int ni = 0; ni < 4; ++ni)
#pragma unroll
            for (int e = 0; e < 4; ++e) acc[mi][ni][e] = 0.f;

    for (int k0 = 0; k0 < DMODEL; k0 += 32) {
        __syncthreads();
#pragma unroll
        for (int p = 0; p < 2; ++p) {
            const int idx = t + p * 256;
            const int r = idx >> 3, c4 = (idx & 7) * 4;
            const size_t off = (size_t)(m0 + r) * DMODEL + k0 + c4;
            const float4 v0 = *(const float4*)(Xp0 + off);
            const float4 v1 = *(const float4*)(Xp1 + off);
            f16x4 hv, lv; _Float16 h, lo;
            split16(v0.x + v1.x, h, lo); hv[0] = h; lv[0] = lo;
            split16(v0.y + v1.y, h, lo); hv[1] = h; lv[1] = lo;
            split16(v0.z + v1.z, h, lo); hv[2] = h; lv[2] = lo;
            split16(v0.w + v1.w, h, lo); hv[3] = h; lv[3] = lo;
            *(f16x4*)&Ah[r][c4] = hv;
            *(f16x4*)&Al[r][c4] = lv;
        }
#pragma unroll
        for (int p = 0; p < 2; ++p) {
            const int idx = t + p * 256;
            const int r = idx >> 2, c8 = (idx & 3) * 8;
            *(f16x8*)&Bh[r][c8] = *(const f16x8*)(WH + (size_t)(n0 + r) * DMODEL + k0 + c8);
            *(f16x8*)&Bl[r][c8] = *(const f16x8*)(WL + (size_t)(n0 + r) * DMODEL + k0 + c8);
        }
        __syncthreads();

        f16x8 ah[2], al[2], bh[4], bl[4];
#pragma unroll
        for (int i = 0; i < 2; ++i) {
            ah[i] = *(f16x8*)&Ah[wm + i * 16 + lr][lk * 8];
            al[i] = *(f16x8*)&Al[wm + i * 16 + lr][lk * 8];
        }
#pragma unroll
        for (int i = 0; i < 4; ++i) {
            bh[i] = *(f16x8*)&Bh[wn + i * 16 + lr][lk * 8];
            bl[i] = *(f16x8*)&Bl[wn + i * 16 + lr][lk * 8];
        }
        __builtin_amdgcn_s_setprio(1);
#pragma unroll
        for (int mi = 0; mi < 2; ++mi)
#pragma unroll
            for (int ni = 0; ni < 4; ++ni) {
                acc[mi][ni] = __builtin_amdgcn_mfma_f32_16x16x32_f16(ah[mi], bh[ni], acc[mi][ni], 0, 0, 0);
                acc[mi][ni] = __builtin_amdgcn_mfma_f32_16x16x32_f16(ah[mi], bl[ni], acc[mi][ni], 0, 0, 0);
                acc[mi][ni] = __builtin_amdgcn_mfma_f32_16x16x32_f16(al[mi], bh[ni], acc[mi][ni], 0, 0, 0);
            }
        __builtin_amdgcn_s_setprio(0);
    }

#pragma unroll
    for (int ni = 0; ni < 4; ++ni) {
        const int col = n0 + wn + ni * 16 + lr;
        const float bv_ = bo[col];
#pragma unroll
        for (int mi = 0; mi < 2; ++mi)
#pragma unroll
            for (int i = 0; i < 4; ++i) {
                const int row = m0 + wm + mi * 16 + lk * 4 + i;
                out[(size_t)row * DMODEL + col] = acc[mi][ni][i] + bv_;
            }
    }
}

extern "C" void kernel_launch(void* const* d_in, const int* in_sizes, int n_in,
                              void* d_out, int out_size, void* d_ws, size_t ws_size,
                              hipStream_t stream) {
    (void)in_sizes; (void)n_in; (void)out_size; (void)ws_size;
    const float* query = (const float*)d_in[0];
    const float* key_  = (const float*)d_in[1];
    const float* value = (const float*)d_in[2];
    const float* Wq = (const float*)d_in[3];
    const float* bq = (const float*)d_in[4];
    const float* Wk = (const float*)d_in[5];
    const float* bk = (const float*)d_in[6];
    const float* Wv = (const float*)d_in[7];
    const float* bv = (const float*)d_in[8];
    const float* Wo = (const float*)d_in[9];
    const float* bo = (const float*)d_in[10];

    float* out  = (float*)d_out;
    float* attn = out + (size_t)NTOK * DMODEL;

    const size_t MM = (size_t)1024 * 1024;
    _Float16* ws16 = (_Float16*)d_ws;          // 48 MB total
    _Float16* Wt  = ws16;                      // 8 planes (Wq,Wk,Wv,Wo x hi/lo), 16 MB
    _Float16* Qh  = ws16 + 8 * MM;             // 6 x 4 MB QKV planes
    _Float16* Ql  = Qh  + 2 * MM;
    _Float16* Kh_ = Ql  + 2 * MM;
    _Float16* Kl_ = Kh_ + 2 * MM;
    _Float16* Vth = Kl_ + 2 * MM;
    _Float16* Vtl = Vth + 2 * MM;

    // dead-after-qkv aliases: Xp0 over Wq/Wk planes; lpart over Wv hi plane
    float* Xp0   = (float*)ws16;                               // 8 MB over Wt[0..4MM)
    float* lpart = (float*)(ws16 + 4 * MM);                    // 512 KB over Wv_hi
    float* Xp1   = (float*)(ws16 + 20 * MM);                   // fresh 8 MB

    // A-split scratch lives in the attn output region (dead until attnpv rewrites it)
    _Float16* As = (_Float16*)attn;                            // 12 MB of 268 MB

    dim3 blk(256);
    prep_w_kernel<<<dim3(32, 32, 4), blk, 0, stream>>>(Wq, Wk, Wv, Wo, Wt);
    prep_a_kernel<<<dim3(1024, 3), blk, 0, stream>>>(query, key_, value, As);
    qkv_mfma_kernel<<<dim3(8, 32, 3), blk, 0, stream>>>(As, Wt, bq, bk, bv,
                                                        Qh, Ql, Kh_, Kl_, Vth, Vtl);
    stats_kernel<<<dim3(16, 16, NCH_S), blk, 0, stream>>>(Qh, Ql, Kh_, lpart);
    attnpv_kernel<<<dim3(16, 16, NCH_A), blk, 0, stream>>>(Qh, Ql, Kh_, Kl_, Vth, Vtl,
                                                           lpart, attn, Xp0, Xp1);
    out_mfma_kernel<<<dim3(8, 32), blk, 0, stream>>>(Xp0, Xp1, Wt + 6 * MM, Wt + 7 * MM, bo, out);
}

// Round 13
// 223.795 us; speedup vs baseline: 1.8722x; 1.0746x over previous
//
#include <hip/hip_runtime.h>
#include <math.h>

#define NTOK 2048
#define DMODEL 1024
#define NHEAD 16
#define DHEAD 64
#define NCH_S 4
#define NCH_A 2
#define TIL_S (NTOK / 64 / NCH_S)   // 8 tiles per stats chunk
#define TIL_A (NTOK / 64 / NCH_A)   // 16 tiles per attnpv chunk

typedef _Float16 f16x8 __attribute__((ext_vector_type(8)));
typedef _Float16 f16x4 __attribute__((ext_vector_type(4)));
typedef _Float16 f16x2 __attribute__((ext_vector_type(2)));
typedef float f32x4 __attribute__((ext_vector_type(4)));
typedef float f32x16 __attribute__((ext_vector_type(16)));

union U32H2 { f16x2 h; unsigned u; };
union U8 { f16x8 v; unsigned u[4]; };

__device__ __forceinline__ void split16(float x, _Float16& hi, _Float16& lo) {
    hi = (_Float16)x;
    lo = (_Float16)(x - (float)hi);
}
__device__ __forceinline__ unsigned packh(_Float16 a, _Float16 b) {
    U32H2 c; c.h = f16x2{a, b}; return c.u;
}

// ---------- prep: W[k][n] f32 -> Wt_hi/Wt_lo [n][k] f16, 4 matrices ----------
__global__ void __launch_bounds__(256) prep_w_kernel(
        const float* __restrict__ Wq, const float* __restrict__ Wk,
        const float* __restrict__ Wv, const float* __restrict__ Wo,
        _Float16* __restrict__ Wt) {
    __shared__ float T[32][33];
    const int z = blockIdx.z;
    const float* W = (z == 0) ? Wq : (z == 1) ? Wk : (z == 2) ? Wv : Wo;
    _Float16* Whi = Wt + (size_t)z * 2 * 1024 * 1024;
    _Float16* Wlo = Whi + (size_t)1024 * 1024;
    const int t = threadIdx.x;
    const int k0 = blockIdx.y * 32, n0 = blockIdx.x * 32;
    const int r = t >> 3, c4 = (t & 7) * 4;
    const float4 v = *(const float4*)(W + (size_t)(k0 + r) * DMODEL + n0 + c4);
    T[r][c4 + 0] = v.x; T[r][c4 + 1] = v.y; T[r][c4 + 2] = v.z; T[r][c4 + 3] = v.w;
    __syncthreads();
    f16x4 hv, lv;
#pragma unroll
    for (int j = 0; j < 4; ++j) {
        _Float16 h, l;
        split16(T[c4 + j][r], h, l);
        hv[j] = h; lv[j] = l;
    }
    *(f16x4*)(Whi + (size_t)(n0 + r) * DMODEL + k0 + c4) = hv;
    *(f16x4*)(Wlo + (size_t)(n0 + r) * DMODEL + k0 + c4) = lv;
}

// ---------- prep: A (query/key/value) f32 -> hi/lo f16 planes ----------
__global__ void __launch_bounds__(256) prep_a_kernel(
        const float* __restrict__ q, const float* __restrict__ k, const float* __restrict__ v,
        _Float16* __restrict__ As) {   // layout: [z][hi/lo][2048*1024]
    const int z = blockIdx.y;
    const float* A = (z == 0) ? q : (z == 1) ? k : v;
    const size_t PL = (size_t)NTOK * DMODEL;
    _Float16* H = As + (size_t)z * 2 * PL;
    _Float16* L = H + PL;
    const size_t off = ((size_t)blockIdx.x * 256 + threadIdx.x) * 8;
    const float4 a = *(const float4*)(A + off);
    const float4 b = *(const float4*)(A + off + 4);
    f16x8 hv, lv; _Float16 h, lo;
    split16(a.x, h, lo); hv[0] = h; lv[0] = lo;
    split16(a.y, h, lo); hv[1] = h; lv[1] = lo;
    split16(a.z, h, lo); hv[2] = h; lv[2] = lo;
    split16(a.w, h, lo); hv[3] = h; lv[3] = lo;
    split16(b.x, h, lo); hv[4] = h; lv[4] = lo;
    split16(b.y, h, lo); hv[5] = h; lv[5] = lo;
    split16(b.z, h, lo); hv[6] = h; lv[6] = lo;
    split16(b.w, h, lo); hv[7] = h; lv[7] = lo;
    *(f16x8*)(H + off) = hv;
    *(f16x8*)(L + off) = lv;
}

// ---------- QKV projection: pre-split f16 MFMA GEMM, 64x128 tile, grid-balanced ----------
__global__ void __launch_bounds__(256) qkv_mfma_kernel(
        const _Float16* __restrict__ As,
        const _Float16* __restrict__ Wt,
        const float* __restrict__ bq, const float* __restrict__ bk, const float* __restrict__ bv,
        _Float16* __restrict__ Qh, _Float16* __restrict__ Ql,
        _Float16* __restrict__ Kh, _Float16* __restrict__ Kl,
        _Float16* __restrict__ Vth, _Float16* __restrict__ Vtl) {
    __shared__ _Float16 Ah[64][40], Al[64][40], Bh[128][40], Bl[128][40];
    const int z = blockIdx.z;
    const size_t PL = (size_t)NTOK * DMODEL;
    const _Float16* AH = As + (size_t)z * 2 * PL;
    const _Float16* AL = AH + PL;
    const _Float16* WH = Wt + (size_t)z * 2 * 1024 * 1024;
    const _Float16* WL = WH + (size_t)1024 * 1024;
    const float* bias = (z == 0) ? bq : (z == 1) ? bk : bv;

    const int t = threadIdx.x;
    const int l = t & 63, wid = t >> 6;
    const int lr = l & 15, lk = l >> 4;
    const int m0 = blockIdx.y * 64, n0 = blockIdx.x * 128;
    const int wm = (wid >> 1) * 32, wn = (wid & 1) * 64;

    f32x4 acc[2][4];
#pragma unroll
    for (int mi = 0; mi < 2; ++mi)
#pragma unroll
        for (int ni = 0; ni < 4; ++ni)
#pragma unroll
            for (int e = 0; e < 4; ++e) acc[mi][ni][e] = 0.f;

    for (int k0 = 0; k0 < DMODEL; k0 += 32) {
        __syncthreads();
        {   // A: pre-split f16, 64x32 per plane
            const int r = t >> 2, c8 = (t & 3) * 8;
            *(f16x8*)&Ah[r][c8] = *(const f16x8*)(AH + (size_t)(m0 + r) * DMODEL + k0 + c8);
            *(f16x8*)&Al[r][c8] = *(const f16x8*)(AL + (size_t)(m0 + r) * DMODEL + k0 + c8);
        }
#pragma unroll
        for (int p = 0; p < 2; ++p) {   // B: 128x32 per plane
            const int idx = t + p * 256;
            const int r = idx >> 2, c8 = (idx & 3) * 8;
            *(f16x8*)&Bh[r][c8] = *(const f16x8*)(WH + (size_t)(n0 + r) * DMODEL + k0 + c8);
            *(f16x8*)&Bl[r][c8] = *(const f16x8*)(WL + (size_t)(n0 + r) * DMODEL + k0 + c8);
        }
        __syncthreads();

        f16x8 ah[2], al[2], bh[4], bl[4];
#pragma unroll
        for (int i = 0; i < 2; ++i) {
            ah[i] = *(f16x8*)&Ah[wm + i * 16 + lr][lk * 8];
            al[i] = *(f16x8*)&Al[wm + i * 16 + lr][lk * 8];
        }
#pragma unroll
        for (int i = 0; i < 4; ++i) {
            bh[i] = *(f16x8*)&Bh[wn + i * 16 + lr][lk * 8];
            bl[i] = *(f16x8*)&Bl[wn + i * 16 + lr][lk * 8];
        }
        __builtin_amdgcn_s_setprio(1);
#pragma unroll
        for (int mi = 0; mi < 2; ++mi)
#pragma unroll
            for (int ni = 0; ni < 4; ++ni) {
                acc[mi][ni] = __builtin_amdgcn_mfma_f32_16x16x32_f16(ah[mi], bh[ni], acc[mi][ni], 0, 0, 0);
                acc[mi][ni] = __builtin_amdgcn_mfma_f32_16x16x32_f16(ah[mi], bl[ni], acc[mi][ni], 0, 0, 0);
                acc[mi][ni] = __builtin_amdgcn_mfma_f32_16x16x32_f16(al[mi], bh[ni], acc[mi][ni], 0, 0, 0);
            }
        __builtin_amdgcn_s_setprio(0);
    }

#pragma unroll
    for (int ni = 0; ni < 4; ++ni) {
        const int col = n0 + wn + ni * 16 + lr;
        const float bv_ = bias[col];
#pragma unroll
        for (int mi = 0; mi < 2; ++mi) {
            if (z == 2) {
                f16x4 hv, lv;
#pragma unroll
                for (int i = 0; i < 4; ++i) {
                    _Float16 h, lo;
                    split16(acc[mi][ni][i] + bv_, h, lo);
                    hv[i] = h; lv[i] = lo;
                }
                const int row = m0 + wm + mi * 16 + lk * 4;
                *(f16x4*)(Vth + (size_t)col * NTOK + row) = hv;
                *(f16x4*)(Vtl + (size_t)col * NTOK + row) = lv;
            } else {
#pragma unroll
                for (int i = 0; i < 4; ++i) {
                    const int row = m0 + wm + mi * 16 + lk * 4 + i;
                    float v = acc[mi][ni][i] + bv_;
                    if (z == 0) v *= 0.125f;
                    _Float16 h, lo;
                    split16(v, h, lo);
                    if (z == 0) { Qh[(size_t)row * DMODEL + col] = h; Ql[(size_t)row * DMODEL + col] = lo; }
                    else        { Kh[(size_t)row * DMODEL + col] = h; Kl[(size_t)row * DMODEL + col] = lo; }
                }
            }
        }
    }
}

// ---------- stats: l = sum exp(s), 2-term split (K hi only), 32x32 swapped QKT ----------
// grid (16, 16, NCH_S); block 256 = 4 waves x 32 q rows. LDS 16KB.
__global__ void __launch_bounds__(256, 4) stats_kernel(
        const _Float16* __restrict__ Qh, const _Float16* __restrict__ Ql,
        const _Float16* __restrict__ Kh,
        float* __restrict__ lpart) {
    __shared__ _Float16 KB[2][64][64];
    const int t = threadIdx.x, l = t & 63, w = t >> 6, q = l & 31, h = l >> 5;
    const int hh = blockIdx.y, z = blockIdx.z;
    const int rw = blockIdx.x * 128 + w * 32;
    const int sr = t >> 3, sc = t & 7;

    f16x8 qbh[4], qbl[4];
#pragma unroll
    for (int s = 0; s < 4; ++s) {
        const size_t off = (size_t)(rw + q) * DMODEL + hh * DHEAD + s * 16 + h * 8;
        qbh[s] = *(const f16x8*)(Qh + off);
        qbl[s] = *(const f16x8*)(Ql + off);
    }

    float lsum = 0.f;
    {
        const int j0 = z * TIL_S * 64;
        const int r = sr, r2 = sr + 32;
        *(f16x8*)&KB[0][r][(sc ^ (r & 7)) * 8]   = *(const f16x8*)(Kh + (size_t)(j0 + r) * DMODEL + hh * DHEAD + sc * 8);
        *(f16x8*)&KB[0][r2][(sc ^ (r2 & 7)) * 8] = *(const f16x8*)(Kh + (size_t)(j0 + r2) * DMODEL + hh * DHEAD + sc * 8);
    }
    for (int it = 0; it < TIL_S; ++it) {
        __syncthreads();
        const int cur = it & 1;
        if (it + 1 < TIL_S) {
            const int j0 = (z * TIL_S + it + 1) * 64;
            const int r = sr, r2 = sr + 32;
            *(f16x8*)&KB[cur ^ 1][r][(sc ^ (r & 7)) * 8]   = *(const f16x8*)(Kh + (size_t)(j0 + r) * DMODEL + hh * DHEAD + sc * 8);
            *(f16x8*)&KB[cur ^ 1][r2][(sc ^ (r2 & 7)) * 8] = *(const f16x8*)(Kh + (size_t)(j0 + r2) * DMODEL + hh * DHEAD + sc * 8);
        }
#pragma unroll
        for (int kb = 0; kb < 2; ++kb) {
            f32x16 c;
#pragma unroll
            for (int r = 0; r < 16; ++r) c[r] = 0.f;
            __builtin_amdgcn_s_setprio(1);
#pragma unroll
            for (int s = 0; s < 4; ++s) {
                const int rk = kb * 32 + q; const int cc = ((2 * s + h) ^ (rk & 7)) * 8;
                const f16x8 ah = *(f16x8*)&KB[cur][rk][cc];
                c = __builtin_amdgcn_mfma_f32_32x32x16_f16(ah, qbh[s], c, 0, 0, 0);
                c = __builtin_amdgcn_mfma_f32_32x32x16_f16(ah, qbl[s], c, 0, 0, 0);
            }
            __builtin_amdgcn_s_setprio(0);
#pragma unroll
            for (int r = 0; r < 16; ++r) lsum += __expf(c[r]);
        }
    }
    lsum += __shfl_xor(lsum, 32);
    if (h == 0) lpart[((size_t)z * NHEAD + hh) * NTOK + rw + q] = lsum;
}

// ---------- attn + PV: slim — 2-term QKT (K hi), 1-term PV (P hi x V hi), 32KB LDS ----------
// grid (16, 16, NCH_A); block 256 = 4 waves x 32 q rows. 4 blocks/CU.
__global__ void __launch_bounds__(256, 4) attnpv_kernel(
        const _Float16* __restrict__ Qh, const _Float16* __restrict__ Ql,
        const _Float16* __restrict__ Kh, const _Float16* __restrict__ Vth,
        const float* __restrict__ lpart,
        float* __restrict__ attn, float* __restrict__ Xp0, float* __restrict__ Xp1) {
    __shared__ _Float16 KB[2][64][64];
    __shared__ _Float16 VB[2][64][64];
    const int t = threadIdx.x, l = t & 63, w = t >> 6, q = l & 31, h = l >> 5;
    const int hh = blockIdx.y, z = blockIdx.z;
    const int rw = blockIdx.x * 128 + w * 32;
    const int sr = t >> 3, sc = t & 7;
    const int qrow = rw + q;

    float lsum = 0.f;
#pragma unroll
    for (int zz = 0; zz < NCH_S; ++zz) lsum += lpart[((size_t)zz * NHEAD + hh) * NTOK + qrow];
    const float linv = 1.f / lsum;

    f16x8 qbh[4], qbl[4];
#pragma unroll
    for (int s = 0; s < 4; ++s) {
        const size_t off = (size_t)qrow * DMODEL + hh * DHEAD + s * 16 + h * 8;
        qbh[s] = *(const f16x8*)(Qh + off);
        qbl[s] = *(const f16x8*)(Ql + off);
    }

    f32x16 x0, x1;
#pragma unroll
    for (int r = 0; r < 16; ++r) { x0[r] = 0.f; x1[r] = 0.f; }

    auto stage = [&](int buf, int j0) {
#pragma unroll
        for (int p = 0; p < 2; ++p) {
            const int r = sr + p * 32; const int cs = (sc ^ (r & 7)) * 8;
            *(f16x8*)&KB[buf][r][cs] = *(const f16x8*)(Kh + (size_t)(j0 + r) * DMODEL + hh * DHEAD + sc * 8);
            *(f16x8*)&VB[buf][r][cs] = *(const f16x8*)(Vth + (size_t)(hh * DHEAD + r) * NTOK + j0 + sc * 8);
        }
    };
    stage(0, z * TIL_A * 64);

    for (int it = 0; it < TIL_A; ++it) {
        const int j0 = (z * TIL_A + it) * 64;
        __syncthreads();
        const int cur = it & 1;
        if (it + 1 < TIL_A) stage(cur ^ 1, (z * TIL_A + it + 1) * 64);

#pragma unroll
        for (int kb = 0; kb < 2; ++kb) {
            f32x16 c;
#pragma unroll
            for (int r = 0; r < 16; ++r) c[r] = 0.f;
            __builtin_amdgcn_s_setprio(1);
#pragma unroll
            for (int s = 0; s < 4; ++s) {
                const int rk = kb * 32 + q; const int cc = ((2 * s + h) ^ (rk & 7)) * 8;
                const f16x8 ah = *(f16x8*)&KB[cur][rk][cc];
                c = __builtin_amdgcn_mfma_f32_32x32x16_f16(ah, qbh[s], c, 0, 0, 0);
                c = __builtin_amdgcn_mfma_f32_32x32x16_f16(ah, qbl[s], c, 0, 0, 0);
            }
            __builtin_amdgcn_s_setprio(0);

            float p[16];
#pragma unroll
            for (int r = 0; r < 16; ++r) p[r] = __expf(c[r]) * linv;

            const int kbase = j0 + kb * 32;
#pragma unroll
            for (int i = 0; i < 4; ++i) {
                f32x4 st;
                st[0] = p[4 * i]; st[1] = p[4 * i + 1]; st[2] = p[4 * i + 2]; st[3] = p[4 * i + 3];
                *(f32x4*)(attn + ((size_t)hh * NTOK + qrow) * NTOK + kbase + 8 * i + 4 * h) = st;
            }

            _Float16 hf[16];
#pragma unroll
            for (int r = 0; r < 16; ++r) hf[r] = (_Float16)p[r];
            unsigned ph[8];
#pragma unroll
            for (int i = 0; i < 8; ++i) ph[i] = packh(hf[2 * i], hf[2 * i + 1]);

#pragma unroll
            for (int ss = 0; ss < 2; ++ss) {
                const int b = 4 * ss;
                const unsigned eh0 = __shfl_xor(h ? ph[b + 0] : ph[b + 2], 32);
                const unsigned eh1 = __shfl_xor(h ? ph[b + 1] : ph[b + 3], 32);
                U8 pah;
                pah.u[0] = h ? eh0 : ph[b + 0]; pah.u[1] = h ? eh1 : ph[b + 1];
                pah.u[2] = h ? ph[b + 2] : eh0; pah.u[3] = h ? ph[b + 3] : eh1;
                const int ks = kb * 2 + ss;
                __builtin_amdgcn_s_setprio(1);
                {
                    const int rd0 = q; const int cv0 = ((2 * ks + h) ^ (rd0 & 7)) * 8;
                    const f16x8 vh = *(f16x8*)&VB[cur][rd0][cv0];
                    x0 = __builtin_amdgcn_mfma_f32_32x32x16_f16(pah.v, vh, x0, 0, 0, 0);
                }
                {
                    const int rd1 = 32 + q; const int cv1 = ((2 * ks + h) ^ (rd1 & 7)) * 8;
                    const f16x8 vh = *(f16x8*)&VB[cur][rd1][cv1];
                    x1 = __builtin_amdgcn_mfma_f32_32x32x16_f16(pah.v, vh, x1, 0, 0, 0);
                }
                __builtin_amdgcn_s_setprio(0);
            }
        }
    }

    float* __restrict__ Xout = z ? Xp1 : Xp0;
#pragma unroll
    for (int r = 0; r < 16; ++r) {
        const int qloc = (r & 3) + 8 * (r >> 2) + 4 * h;
        Xout[(size_t)(rw + qloc) * DMODEL + hh * DHEAD + q]      = x0[r];
        Xout[(size_t)(rw + qloc) * DMODEL + hh * DHEAD + 32 + q] = x1[r];
    }
}

// ---------- output projection: A = Xp0+Xp1 (f32) -> split, 64x128 tile ----------
__global__ void __launch_bounds__(256) out_mfma_kernel(
        const float* __restrict__ Xp0, const float* __restrict__ Xp1,
        const _Float16* __restrict__ WH, const _Float16* __restrict__ WL,
        const float* __restrict__ bo, float* __restrict__ out) {
    __shared__ _Float16 Ah[64][40], Al[64][40], Bh[128][40], Bl[128][40];
    const int t = threadIdx.x;
    const int l = t & 63, wid = t >> 6;
    const int lr = l & 15, lk = l >> 4;
    const int m0 = blockIdx.y * 64, n0 = blockIdx.x * 128;
    const int wm = (wid >> 1) * 32, wn = (wid & 1) * 64;

    f32x4 acc[2][4];
#pragma unroll
    for (int mi = 0; mi < 2; ++mi)
#pragma unroll
        for (int ni = 0; ni < 4; ++ni)
#pragma unroll
            for (int e = 0; e < 4; ++e) acc[mi][ni][e] = 0.f;

    for (int k0 = 0; k0 < DMODEL; k0 += 32) {
        __syncthreads();
#pragma unroll
        for (int p = 0; p < 2; ++p) {
            const int idx = t + p * 256;
            const int r = idx >> 3, c4 = (idx & 7) * 4;
            const size_t off = (size_t)(m0 + r) * DMODEL + k0 + c4;
            const float4 v0 = *(const float4*)(Xp0 + off);
            const float4 v1 = *(const float4*)(Xp1 + off);
            f16x4 hv, lv; _Float16 h, lo;
            split16(v0.x + v1.x, h, lo); hv[0] = h; lv[0] = lo;
            split16(v0.y + v1.y, h, lo); hv[1] = h; lv[1] = lo;
            split16(v0.z + v1.z, h, lo); hv[2] = h; lv[2] = lo;
            split16(v0.w + v1.w, h, lo); hv[3] = h; lv[3] = lo;
            *(f16x4*)&Ah[r][c4] = hv;
            *(f16x4*)&Al[r][c4] = lv;
        }
#pragma unroll
        for (int p = 0; p < 2; ++p) {
            const int idx = t + p * 256;
            const int r = idx >> 2, c8 = (idx & 3) * 8;
            *(f16x8*)&Bh[r][c8] = *(const f16x8*)(WH + (size_t)(n0 + r) * DMODEL + k0 + c8);
            *(f16x8*)&Bl[r][c8] = *(const f16x8*)(WL + (size_t)(n0 + r) * DMODEL + k0 + c8);
        }
        __syncthreads();

        f16x8 ah[2], al[2], bh[4], bl[4];
#pragma unroll
        for (int i = 0; i < 2; ++i) {
            ah[i] = *(f16x8*)&Ah[wm + i * 16 + lr][lk * 8];
            al[i] = *(f16x8*)&Al[wm + i * 16 + lr][lk * 8];
        }
#pragma unroll
        for (int i = 0; i < 4; ++i) {
            bh[i] = *(f16x8*)&Bh[wn + i * 16 + lr][lk * 8];
            bl[i] = *(f16x8*)&Bl[wn + i * 16 + lr][lk * 8];
        }
        __builtin_amdgcn_s_setprio(1);
#pragma unroll
        for (int mi = 0; mi < 2; ++mi)
#pragma unroll
            for (int ni = 0; ni < 4; ++ni) {
                acc[mi][ni] = __builtin_amdgcn_mfma_f32_16x16x32_f16(ah[mi], bh[ni], acc[mi][ni], 0, 0, 0);
                acc[mi][ni] = __builtin_amdgcn_mfma_f32_16x16x32_f16(ah[mi], bl[ni], acc[mi][ni], 0, 0, 0);
                acc[mi][ni] = __builtin_amdgcn_mfma_f32_16x16x32_f16(al[mi], bh[ni], acc[mi][ni], 0, 0, 0);
            }
        __builtin_amdgcn_s_setprio(0);
    }

#pragma unroll
    for (int ni = 0; ni < 4; ++ni) {
        const int col = n0 + wn + ni * 16 + lr;
        const float bv_ = bo[col];
#pragma unroll
        for (int mi = 0; mi < 2; ++mi)
#pragma unroll
            for (int i = 0; i < 4; ++i) {
                const int row = m0 + wm + mi * 16 + lk * 4 + i;
                out[(size_t)row * DMODEL + col] = acc[mi][ni][i] + bv_;
            }
    }
}

extern "C" void kernel_launch(void* const* d_in, const int* in_sizes, int n_in,
                              void* d_out, int out_size, void* d_ws, size_t ws_size,
                              hipStream_t stream) {
    (void)in_sizes; (void)n_in; (void)out_size; (void)ws_size;
    const float* query = (const float*)d_in[0];
    const float* key_  = (const float*)d_in[1];
    const float* value = (const float*)d_in[2];
    const float* Wq = (const float*)d_in[3];
    const float* bq = (const float*)d_in[4];
    const float* Wk = (const float*)d_in[5];
    const float* bk = (const float*)d_in[6];
    const float* Wv = (const float*)d_in[7];
    const float* bv = (const float*)d_in[8];
    const float* Wo = (const float*)d_in[9];
    const float* bo = (const float*)d_in[10];

    float* out  = (float*)d_out;
    float* attn = out + (size_t)NTOK * DMODEL;

    const size_t MM = (size_t)1024 * 1024;
    _Float16* ws16 = (_Float16*)d_ws;          // 48 MB total
    _Float16* Wt  = ws16;                      // 8 planes (Wq,Wk,Wv,Wo x hi/lo), 16 MB
    _Float16* Qh  = ws16 + 8 * MM;             // 6 x 4 MB QKV planes
    _Float16* Ql  = Qh  + 2 * MM;
    _Float16* Kh_ = Ql  + 2 * MM;
    _Float16* Kl_ = Kh_ + 2 * MM;
    _Float16* Vth = Kl_ + 2 * MM;
    _Float16* Vtl = Vth + 2 * MM;

    // dead-after-qkv aliases: Xp0 over Wq/Wk planes; lpart over Wv hi plane
    float* Xp0   = (float*)ws16;                               // 8 MB over Wt[0..4MM)
    float* lpart = (float*)(ws16 + 4 * MM);                    // 512 KB over Wv_hi
    float* Xp1   = (float*)(ws16 + 20 * MM);                   // fresh 8 MB

    // A-split scratch lives in the attn output region (dead until attnpv rewrites it)
    _Float16* As = (_Float16*)attn;                            // 12 MB of 268 MB

    dim3 blk(256);
    prep_w_kernel<<<dim3(32, 32, 4), blk, 0, stream>>>(Wq, Wk, Wv, Wo, Wt);
    prep_a_kernel<<<dim3(1024, 3), blk, 0, stream>>>(query, key_, value, As);
    qkv_mfma_kernel<<<dim3(8, 32, 3), blk, 0, stream>>>(As, Wt, bq, bk, bv,
                                                        Qh, Ql, Kh_, Kl_, Vth, Vtl);
    stats_kernel<<<dim3(16, 16, NCH_S), blk, 0, stream>>>(Qh, Ql, Kh_, lpart);
    attnpv_kernel<<<dim3(16, 16, NCH_A), blk, 0, stream>>>(Qh, Ql, Kh_, Vth,
                                                           lpart, attn, Xp0, Xp1);
    out_mfma_kernel<<<dim3(8, 32), blk, 0, stream>>>(Xp0, Xp1, Wt + 6 * MM, Wt + 7 * MM, bo, out);
}

// Round 14
// 217.821 us; speedup vs baseline: 1.9236x; 1.0274x over previous
//
#include <hip/hip_runtime.h>
#include <math.h>

#define NTOK 2048
#define DMODEL 1024
#define NHEAD 16
#define DHEAD 64
#define NTIL (NTOK / 64)   // 32 K-tiles

typedef _Float16 f16x8 __attribute__((ext_vector_type(8)));
typedef _Float16 f16x4 __attribute__((ext_vector_type(4)));
typedef _Float16 f16x2 __attribute__((ext_vector_type(2)));
typedef float f32x4 __attribute__((ext_vector_type(4)));
typedef float f32x16 __attribute__((ext_vector_type(16)));

union U32H2 { f16x2 h; unsigned u; };
union U8 { f16x8 v; unsigned u[4]; };

__device__ __forceinline__ void split16(float x, _Float16& hi, _Float16& lo) {
    hi = (_Float16)x;
    lo = (_Float16)(x - (float)hi);
}
__device__ __forceinline__ unsigned packh(_Float16 a, _Float16 b) {
    U32H2 c; c.h = f16x2{a, b}; return c.u;
}

// ---------- prep: W[k][n] f32 -> Wt_hi/Wt_lo [n][k] f16, 4 matrices ----------
__global__ void __launch_bounds__(256) prep_w_kernel(
        const float* __restrict__ Wq, const float* __restrict__ Wk,
        const float* __restrict__ Wv, const float* __restrict__ Wo,
        _Float16* __restrict__ Wt) {
    __shared__ float T[32][33];
    const int z = blockIdx.z;
    const float* W = (z == 0) ? Wq : (z == 1) ? Wk : (z == 2) ? Wv : Wo;
    _Float16* Whi = Wt + (size_t)z * 2 * 1024 * 1024;
    _Float16* Wlo = Whi + (size_t)1024 * 1024;
    const int t = threadIdx.x;
    const int k0 = blockIdx.y * 32, n0 = blockIdx.x * 32;
    const int r = t >> 3, c4 = (t & 7) * 4;
    const float4 v = *(const float4*)(W + (size_t)(k0 + r) * DMODEL + n0 + c4);
    T[r][c4 + 0] = v.x; T[r][c4 + 1] = v.y; T[r][c4 + 2] = v.z; T[r][c4 + 3] = v.w;
    __syncthreads();
    f16x4 hv, lv;
#pragma unroll
    for (int j = 0; j < 4; ++j) {
        _Float16 h, l;
        split16(T[c4 + j][r], h, l);
        hv[j] = h; lv[j] = l;
    }
    *(f16x4*)(Whi + (size_t)(n0 + r) * DMODEL + k0 + c4) = hv;
    *(f16x4*)(Wlo + (size_t)(n0 + r) * DMODEL + k0 + c4) = lv;
}

// ---------- prep: A (query/key/value) f32 -> hi/lo f16 planes ----------
__global__ void __launch_bounds__(256) prep_a_kernel(
        const float* __restrict__ q, const float* __restrict__ k, const float* __restrict__ v,
        _Float16* __restrict__ As) {   // layout: [z][hi/lo][2048*1024]
    const int z = blockIdx.y;
    const float* A = (z == 0) ? q : (z == 1) ? k : v;
    const size_t PL = (size_t)NTOK * DMODEL;
    _Float16* H = As + (size_t)z * 2 * PL;
    _Float16* L = H + PL;
    const size_t off = ((size_t)blockIdx.x * 256 + threadIdx.x) * 8;
    const float4 a = *(const float4*)(A + off);
    const float4 b = *(const float4*)(A + off + 4);
    f16x8 hv, lv; _Float16 h, lo;
    split16(a.x, h, lo); hv[0] = h; lv[0] = lo;
    split16(a.y, h, lo); hv[1] = h; lv[1] = lo;
    split16(a.z, h, lo); hv[2] = h; lv[2] = lo;
    split16(a.w, h, lo); hv[3] = h; lv[3] = lo;
    split16(b.x, h, lo); hv[4] = h; lv[4] = lo;
    split16(b.y, h, lo); hv[5] = h; lv[5] = lo;
    split16(b.z, h, lo); hv[6] = h; lv[6] = lo;
    split16(b.w, h, lo); hv[7] = h; lv[7] = lo;
    *(f16x8*)(H + off) = hv;
    *(f16x8*)(L + off) = lv;
}

// ---------- QKV projection: pre-split f16 MFMA GEMM, 64x128 tile, grid-balanced ----------
// Outputs: z=0 -> Qh+Ql (x0.125); z=1 -> Kh only; z=2 -> Vth only.
__global__ void __launch_bounds__(256) qkv_mfma_kernel(
        const _Float16* __restrict__ As,
        const _Float16* __restrict__ Wt,
        const float* __restrict__ bq, const float* __restrict__ bk, const float* __restrict__ bv,
        _Float16* __restrict__ Qh, _Float16* __restrict__ Ql,
        _Float16* __restrict__ Kh, _Float16* __restrict__ Vth) {
    __shared__ _Float16 Ah[64][40], Al[64][40], Bh[128][40], Bl[128][40];
    const int z = blockIdx.z;
    const size_t PL = (size_t)NTOK * DMODEL;
    const _Float16* AH = As + (size_t)z * 2 * PL;
    const _Float16* AL = AH + PL;
    const _Float16* WH = Wt + (size_t)z * 2 * 1024 * 1024;
    const _Float16* WL = WH + (size_t)1024 * 1024;
    const float* bias = (z == 0) ? bq : (z == 1) ? bk : bv;

    const int t = threadIdx.x;
    const int l = t & 63, wid = t >> 6;
    const int lr = l & 15, lk = l >> 4;
    const int m0 = blockIdx.y * 64, n0 = blockIdx.x * 128;
    const int wm = (wid >> 1) * 32, wn = (wid & 1) * 64;

    f32x4 acc[2][4];
#pragma unroll
    for (int mi = 0; mi < 2; ++mi)
#pragma unroll
        for (int ni = 0; ni < 4; ++ni)
#pragma unroll
            for (int e = 0; e < 4; ++e) acc[mi][ni][e] = 0.f;

    for (int k0 = 0; k0 < DMODEL; k0 += 32) {
        __syncthreads();
        {   // A: pre-split f16, 64x32 per plane
            const int r = t >> 2, c8 = (t & 3) * 8;
            *(f16x8*)&Ah[r][c8] = *(const f16x8*)(AH + (size_t)(m0 + r) * DMODEL + k0 + c8);
            *(f16x8*)&Al[r][c8] = *(const f16x8*)(AL + (size_t)(m0 + r) * DMODEL + k0 + c8);
        }
#pragma unroll
        for (int p = 0; p < 2; ++p) {   // B: 128x32 per plane
            const int idx = t + p * 256;
            const int r = idx >> 2, c8 = (idx & 3) * 8;
            *(f16x8*)&Bh[r][c8] = *(const f16x8*)(WH + (size_t)(n0 + r) * DMODEL + k0 + c8);
            *(f16x8*)&Bl[r][c8] = *(const f16x8*)(WL + (size_t)(n0 + r) * DMODEL + k0 + c8);
        }
        __syncthreads();

        f16x8 ah[2], al[2], bh[4], bl[4];
#pragma unroll
        for (int i = 0; i < 2; ++i) {
            ah[i] = *(f16x8*)&Ah[wm + i * 16 + lr][lk * 8];
            al[i] = *(f16x8*)&Al[wm + i * 16 + lr][lk * 8];
        }
#pragma unroll
        for (int i = 0; i < 4; ++i) {
            bh[i] = *(f16x8*)&Bh[wn + i * 16 + lr][lk * 8];
            bl[i] = *(f16x8*)&Bl[wn + i * 16 + lr][lk * 8];
        }
        __builtin_amdgcn_s_setprio(1);
#pragma unroll
        for (int mi = 0; mi < 2; ++mi)
#pragma unroll
            for (int ni = 0; ni < 4; ++ni) {
                acc[mi][ni] = __builtin_amdgcn_mfma_f32_16x16x32_f16(ah[mi], bh[ni], acc[mi][ni], 0, 0, 0);
                acc[mi][ni] = __builtin_amdgcn_mfma_f32_16x16x32_f16(ah[mi], bl[ni], acc[mi][ni], 0, 0, 0);
                acc[mi][ni] = __builtin_amdgcn_mfma_f32_16x16x32_f16(al[mi], bh[ni], acc[mi][ni], 0, 0, 0);
            }
        __builtin_amdgcn_s_setprio(0);
    }

#pragma unroll
    for (int ni = 0; ni < 4; ++ni) {
        const int col = n0 + wn + ni * 16 + lr;
        const float bv_ = bias[col];
#pragma unroll
        for (int mi = 0; mi < 2; ++mi) {
            if (z == 2) {
                f16x4 hv;
#pragma unroll
                for (int i = 0; i < 4; ++i) hv[i] = (_Float16)(acc[mi][ni][i] + bv_);
                const int row = m0 + wm + mi * 16 + lk * 4;
                *(f16x4*)(Vth + (size_t)col * NTOK + row) = hv;
            } else {
#pragma unroll
                for (int i = 0; i < 4; ++i) {
                    const int row = m0 + wm + mi * 16 + lk * 4 + i;
                    float v = acc[mi][ni][i] + bv_;
                    if (z == 0) {
                        v *= 0.125f;
                        _Float16 h, lo;
                        split16(v, h, lo);
                        Qh[(size_t)row * DMODEL + col] = h;
                        Ql[(size_t)row * DMODEL + col] = lo;
                    } else {
                        Kh[(size_t)row * DMODEL + col] = (_Float16)v;
                    }
                }
            }
        }
    }
}

// ---------- fused attention: pass1 computes l, pass2 writes attn + PV ----------
// grid (16, 16): x = q-block of 128 rows (4 waves x 32), y = head. 1 block/CU.
__global__ void __launch_bounds__(256, 2) fused_attn_kernel(
        const _Float16* __restrict__ Qh, const _Float16* __restrict__ Ql,
        const _Float16* __restrict__ Kh, const _Float16* __restrict__ Vth,
        float* __restrict__ attn, float* __restrict__ Xp) {
    __shared__ _Float16 KB[2][64][64];
    __shared__ _Float16 VB[2][64][64];
    const int t = threadIdx.x, l = t & 63, w = t >> 6, q = l & 31, h = l >> 5;
    const int hh = blockIdx.y;
    const int rw = blockIdx.x * 128 + w * 32;
    const int sr = t >> 3, sc = t & 7;
    const int qrow = rw + q;

    f16x8 qbh[4], qbl[4];
#pragma unroll
    for (int s = 0; s < 4; ++s) {
        const size_t off = (size_t)qrow * DMODEL + hh * DHEAD + s * 16 + h * 8;
        qbh[s] = *(const f16x8*)(Qh + off);
        qbl[s] = *(const f16x8*)(Ql + off);
    }

    auto stageK = [&](int buf, int j0) {
#pragma unroll
        for (int p = 0; p < 2; ++p) {
            const int r = sr + p * 32; const int cs = (sc ^ (r & 7)) * 8;
            *(f16x8*)&KB[buf][r][cs] = *(const f16x8*)(Kh + (size_t)(j0 + r) * DMODEL + hh * DHEAD + sc * 8);
        }
    };
    auto stageKV = [&](int buf, int j0) {
#pragma unroll
        for (int p = 0; p < 2; ++p) {
            const int r = sr + p * 32; const int cs = (sc ^ (r & 7)) * 8;
            *(f16x8*)&KB[buf][r][cs] = *(const f16x8*)(Kh + (size_t)(j0 + r) * DMODEL + hh * DHEAD + sc * 8);
            *(f16x8*)&VB[buf][r][cs] = *(const f16x8*)(Vth + (size_t)(hh * DHEAD + r) * NTOK + j0 + sc * 8);
        }
    };

    // ---- pass 1: l = sum exp(s) (2-term QK^T, identical MFMA sequence to pass 2) ----
    float lsum = 0.f;
    stageK(0, 0);
    for (int it = 0; it < NTIL; ++it) {
        __syncthreads();
        const int cur = it & 1;
        if (it + 1 < NTIL) stageK(cur ^ 1, (it + 1) * 64);
#pragma unroll
        for (int kb = 0; kb < 2; ++kb) {
            f32x16 c;
#pragma unroll
            for (int r = 0; r < 16; ++r) c[r] = 0.f;
            __builtin_amdgcn_s_setprio(1);
#pragma unroll
            for (int s = 0; s < 4; ++s) {
                const int rk = kb * 32 + q; const int cc = ((2 * s + h) ^ (rk & 7)) * 8;
                const f16x8 ah = *(f16x8*)&KB[cur][rk][cc];
                c = __builtin_amdgcn_mfma_f32_32x32x16_f16(ah, qbh[s], c, 0, 0, 0);
                c = __builtin_amdgcn_mfma_f32_32x32x16_f16(ah, qbl[s], c, 0, 0, 0);
            }
            __builtin_amdgcn_s_setprio(0);
#pragma unroll
            for (int r = 0; r < 16; ++r) lsum += __expf(c[r]);
        }
    }
    lsum += __shfl_xor(lsum, 32);
    const float linv = 1.f / lsum;

    // ---- pass 2: recompute s, write attn, PV ----
    f32x16 x0, x1;
#pragma unroll
    for (int r = 0; r < 16; ++r) { x0[r] = 0.f; x1[r] = 0.f; }

    __syncthreads();               // all pass-1 LDS reads complete
    stageKV(0, 0);
    for (int it = 0; it < NTIL; ++it) {
        const int j0 = it * 64;
        __syncthreads();
        const int cur = it & 1;
        if (it + 1 < NTIL) stageKV(cur ^ 1, (it + 1) * 64);

#pragma unroll
        for (int kb = 0; kb < 2; ++kb) {
            f32x16 c;
#pragma unroll
            for (int r = 0; r < 16; ++r) c[r] = 0.f;
            __builtin_amdgcn_s_setprio(1);
#pragma unroll
            for (int s = 0; s < 4; ++s) {
                const int rk = kb * 32 + q; const int cc = ((2 * s + h) ^ (rk & 7)) * 8;
                const f16x8 ah = *(f16x8*)&KB[cur][rk][cc];
                c = __builtin_amdgcn_mfma_f32_32x32x16_f16(ah, qbh[s], c, 0, 0, 0);
                c = __builtin_amdgcn_mfma_f32_32x32x16_f16(ah, qbl[s], c, 0, 0, 0);
            }
            __builtin_amdgcn_s_setprio(0);

            float p[16];
#pragma unroll
            for (int r = 0; r < 16; ++r) p[r] = __expf(c[r]) * linv;

            const int kbase = j0 + kb * 32;
#pragma unroll
            for (int i = 0; i < 4; ++i) {
                f32x4 st;
                st[0] = p[4 * i]; st[1] = p[4 * i + 1]; st[2] = p[4 * i + 2]; st[3] = p[4 * i + 3];
                *(f32x4*)(attn + ((size_t)hh * NTOK + qrow) * NTOK + kbase + 8 * i + 4 * h) = st;
            }

            _Float16 hf[16];
#pragma unroll
            for (int r = 0; r < 16; ++r) hf[r] = (_Float16)p[r];
            unsigned ph[8];
#pragma unroll
            for (int i = 0; i < 8; ++i) ph[i] = packh(hf[2 * i], hf[2 * i + 1]);

#pragma unroll
            for (int ss = 0; ss < 2; ++ss) {
                const int b = 4 * ss;
                const unsigned eh0 = __shfl_xor(h ? ph[b + 0] : ph[b + 2], 32);
                const unsigned eh1 = __shfl_xor(h ? ph[b + 1] : ph[b + 3], 32);
                U8 pah;
                pah.u[0] = h ? eh0 : ph[b + 0]; pah.u[1] = h ? eh1 : ph[b + 1];
                pah.u[2] = h ? ph[b + 2] : eh0; pah.u[3] = h ? ph[b + 3] : eh1;
                const int ks = kb * 2 + ss;
                __builtin_amdgcn_s_setprio(1);
                {
                    const int rd0 = q; const int cv0 = ((2 * ks + h) ^ (rd0 & 7)) * 8;
                    const f16x8 vh = *(f16x8*)&VB[cur][rd0][cv0];
                    x0 = __builtin_amdgcn_mfma_f32_32x32x16_f16(pah.v, vh, x0, 0, 0, 0);
                }
                {
                    const int rd1 = 32 + q; const int cv1 = ((2 * ks + h) ^ (rd1 & 7)) * 8;
                    const f16x8 vh = *(f16x8*)&VB[cur][rd1][cv1];
                    x1 = __builtin_amdgcn_mfma_f32_32x32x16_f16(pah.v, vh, x1, 0, 0, 0);
                }
                __builtin_amdgcn_s_setprio(0);
            }
        }
    }

#pragma unroll
    for (int r = 0; r < 16; ++r) {
        const int qloc = (r & 3) + 8 * (r >> 2) + 4 * h;
        Xp[(size_t)(rw + qloc) * DMODEL + hh * DHEAD + q]      = x0[r];
        Xp[(size_t)(rw + qloc) * DMODEL + hh * DHEAD + 32 + q] = x1[r];
    }
}

// ---------- output projection: A = Xp (f32) -> split, 64x128 tile ----------
__global__ void __launch_bounds__(256) out_mfma_kernel(
        const float* __restrict__ Xp,
        const _Float16* __restrict__ WH, const _Float16* __restrict__ WL,
        const float* __restrict__ bo, float* __restrict__ out) {
    __shared__ _Float16 Ah[64][40], Al[64][40], Bh[128][40], Bl[128][40];
    const int t = threadIdx.x;
    const int l = t & 63, wid = t >> 6;
    const int lr = l & 15, lk = l >> 4;
    const int m0 = blockIdx.y * 64, n0 = blockIdx.x * 128;
    const int wm = (wid >> 1) * 32, wn = (wid & 1) * 64;

    f32x4 acc[2][4];
#pragma unroll
    for (int mi = 0; mi < 2; ++mi)
#pragma unroll
        for (int ni = 0; ni < 4; ++ni)
#pragma unroll
            for (int e = 0; e < 4; ++e) acc[mi][ni][e] = 0.f;

    for (int k0 = 0; k0 < DMODEL; k0 += 32) {
        __syncthreads();
#pragma unroll
        for (int p = 0; p < 2; ++p) {
            const int idx = t + p * 256;
            const int r = idx >> 3, c4 = (idx & 7) * 4;
            const size_t off = (size_t)(m0 + r) * DMODEL + k0 + c4;
            const float4 v0 = *(const float4*)(Xp + off);
            f16x4 hv, lv; _Float16 h, lo;
            split16(v0.x, h, lo); hv[0] = h; lv[0] = lo;
            split16(v0.y, h, lo); hv[1] = h; lv[1] = lo;
            split16(v0.z, h, lo); hv[2] = h; lv[2] = lo;
            split16(v0.w, h, lo); hv[3] = h; lv[3] = lo;
            *(f16x4*)&Ah[r][c4] = hv;
            *(f16x4*)&Al[r][c4] = lv;
        }
#pragma unroll
        for (int p = 0; p < 2; ++p) {
            const int idx = t + p * 256;
            const int r = idx >> 2, c8 = (idx & 3) * 8;
            *(f16x8*)&Bh[r][c8] = *(const f16x8*)(WH + (size_t)(n0 + r) * DMODEL + k0 + c8);
            *(f16x8*)&Bl[r][c8] = *(const f16x8*)(WL + (size_t)(n0 + r) * DMODEL + k0 + c8);
        }
        __syncthreads();

        f16x8 ah[2], al[2], bh[4], bl[4];
#pragma unroll
        for (int i = 0; i < 2; ++i) {
            ah[i] = *(f16x8*)&Ah[wm + i * 16 + lr][lk * 8];
            al[i] = *(f16x8*)&Al[wm + i * 16 + lr][lk * 8];
        }
#pragma unroll
        for (int i = 0; i < 4; ++i) {
            bh[i] = *(f16x8*)&Bh[wn + i * 16 + lr][lk * 8];
            bl[i] = *(f16x8*)&Bl[wn + i * 16 + lr][lk * 8];
        }
        __builtin_amdgcn_s_setprio(1);
#pragma unroll
        for (int mi = 0; mi < 2; ++mi)
#pragma unroll
            for (int ni = 0; ni < 4; ++ni) {
                acc[mi][ni] = __builtin_amdgcn_mfma_f32_16x16x32_f16(ah[mi], bh[ni], acc[mi][ni], 0, 0, 0);
                acc[mi][ni] = __builtin_amdgcn_mfma_f32_16x16x32_f16(ah[mi], bl[ni], acc[mi][ni], 0, 0, 0);
                acc[mi][ni] = __builtin_amdgcn_mfma_f32_16x16x32_f16(al[mi], bh[ni], acc[mi][ni], 0, 0, 0);
            }
        __builtin_amdgcn_s_setprio(0);
    }

#pragma unroll
    for (int ni = 0; ni < 4; ++ni) {
        const int col = n0 + wn + ni * 16 + lr;
        const float bv_ = bo[col];
#pragma unroll
        for (int mi = 0; mi < 2; ++mi)
#pragma unroll
            for (int i = 0; i < 4; ++i) {
                const int row = m0 + wm + mi * 16 + lk * 4 + i;
                out[(size_t)row * DMODEL + col] = acc[mi][ni][i] + bv_;
            }
    }
}

extern "C" void kernel_launch(void* const* d_in, const int* in_sizes, int n_in,
                              void* d_out, int out_size, void* d_ws, size_t ws_size,
                              hipStream_t stream) {
    (void)in_sizes; (void)n_in; (void)out_size; (void)ws_size;
    const float* query = (const float*)d_in[0];
    const float* key_  = (const float*)d_in[1];
    const float* value = (const float*)d_in[2];
    const float* Wq = (const float*)d_in[3];
    const float* bq = (const float*)d_in[4];
    const float* Wk = (const float*)d_in[5];
    const float* bk = (const float*)d_in[6];
    const float* Wv = (const float*)d_in[7];
    const float* bv = (const float*)d_in[8];
    const float* Wo = (const float*)d_in[9];
    const float* bo = (const float*)d_in[10];

    float* out  = (float*)d_out;
    float* attn = out + (size_t)NTOK * DMODEL;

    const size_t MM = (size_t)1024 * 1024;
    _Float16* ws16 = (_Float16*)d_ws;          // 32 MB used
    _Float16* Wt  = ws16;                      // 8 planes (Wq,Wk,Wv,Wo x hi/lo), 16 MB
    _Float16* Qh  = ws16 + 8 * MM;             // 4 x 4 MB planes
    _Float16* Ql  = Qh  + 2 * MM;
    _Float16* Kh_ = Ql  + 2 * MM;
    _Float16* Vth = Kh_ + 2 * MM;

    // dead-after-qkv alias: Xp (8 MB) over Wq/Wk hi planes
    float* Xp = (float*)ws16;

    // A-split scratch lives in the attn output region (dead until fused_attn rewrites it)
    _Float16* As = (_Float16*)attn;            // 12 MB of 268 MB

    dim3 blk(256);
    prep_w_kernel<<<dim3(32, 32, 4), blk, 0, stream>>>(Wq, Wk, Wv, Wo, Wt);
    prep_a_kernel<<<dim3(1024, 3), blk, 0, stream>>>(query, key_, value, As);
    qkv_mfma_kernel<<<dim3(8, 32, 3), blk, 0, stream>>>(As, Wt, bq, bk, bv,
                                                        Qh, Ql, Kh_, Vth);
    fused_attn_kernel<<<dim3(16, 16), blk, 0, stream>>>(Qh, Ql, Kh_, Vth, attn, Xp);
    out_mfma_kernel<<<dim3(8, 32), blk, 0, stream>>>(Xp, Wt + 6 * MM, Wt + 7 * MM, bo, out);
}